// Round 16
// baseline (531.714 us; speedup 1.0000x reference)
//
#include <hip/hip_runtime.h>

static constexpr int BATCH  = 2;
static constexpr int SEQ    = 2048;
static constexpr int DMODEL = 1024;
static constexpr int NHEADS = 16;
static constexpr int EHEAD  = 64;
static constexpr int DFF    = 4096;
static constexpr int NTOP   = 40;

typedef unsigned short u16;
typedef __bf16 bf16x8_t __attribute__((ext_vector_type(8)));
typedef u16    u16x8_t  __attribute__((ext_vector_type(8)));
typedef u16    u16x4_t  __attribute__((ext_vector_type(4)));
typedef float  f32x4_t  __attribute__((ext_vector_type(4)));

static constexpr float QSCALE = 0.125f * 1.44269504088896f;  // 1/8 * log2(e)
static constexpr float FIXM   = 12.0f;  // fixed softmax shift (log2 domain)

static __device__ __forceinline__ u16 f2b(float f) {
  unsigned u = __builtin_bit_cast(unsigned, f);
  unsigned r = u + 0x7FFFu + ((u >> 16) & 1u);
  return (u16)(r >> 16);
}
static __device__ __forceinline__ u16 f2bf(float f) {
  __bf16 h = (__bf16)f;
  return __builtin_bit_cast(u16, h);
}
static __device__ __forceinline__ float b2f(u16 h) {
  unsigned u = ((unsigned)h) << 16;
  return __builtin_bit_cast(float, u);
}
static __device__ __forceinline__ f32x4_t mfma_bf16(u16x8_t a, u16x8_t b, f32x4_t c) {
  return __builtin_amdgcn_mfma_f32_16x16x32_bf16(
      __builtin_bit_cast(bf16x8_t, a), __builtin_bit_cast(bf16x8_t, b), c, 0, 0, 0);
}

#define GLD16(gsrc, ldst)                                                        \
  __builtin_amdgcn_global_load_lds(                                             \
      (const __attribute__((address_space(1))) void*)(gsrc),                    \
      (__attribute__((address_space(3))) void*)(ldst), 16, 0, 0)

// ---------------------------------------------------------------- threefry
static __device__ __forceinline__ void tf2x32(unsigned k0, unsigned k1,
                                              unsigned x0, unsigned x1,
                                              unsigned& o0, unsigned& o1) {
  unsigned ks2 = 0x1BD11BDAu ^ k0 ^ k1;
  x0 += k0; x1 += k1;
#define TFR(r) { x0 += x1; x1 = (x1 << r) | (x1 >> (32 - r)); x1 ^= x0; }
  TFR(13) TFR(15) TFR(26) TFR(6)  x0 += k1;  x1 += ks2 + 1u;
  TFR(17) TFR(29) TFR(16) TFR(24) x0 += ks2; x1 += k0 + 2u;
  TFR(13) TFR(15) TFR(26) TFR(6)  x0 += k0;  x1 += k1 + 3u;
  TFR(17) TFR(29) TFR(16) TFR(24) x0 += k1;  x1 += ks2 + 4u;
  TFR(13) TFR(15) TFR(26) TFR(6)  x0 += ks2; x1 += k0 + 5u;
#undef TFR
  o0 = x0; o1 = x1;
}

// ---------------------------------------------------------------- prep (merged)
__global__ __launch_bounds__(256)
void prep_misc(const float* __restrict__ x, u16* __restrict__ xh,
               u16* __restrict__ xl, const float* __restrict__ mem,
               u16* __restrict__ memb, int* __restrict__ idx,
               const float* __restrict__ sbq, const float* __restrict__ sbk,
               float* __restrict__ biasqk, const float* __restrict__ cbk,
               const float* __restrict__ cbv, float* __restrict__ cbkv) {
  int blk = blockIdx.x, tid = threadIdx.x;
  if (blk < 4096) {
    int i = blk * 256 + tid;
    f32x4_t v = *(const f32x4_t*)(x + (size_t)i * 4);
    u16x4_t h, l;
#pragma unroll
    for (int d = 0; d < 4; ++d) {
      u16 hh = f2b(v[d]); h[d] = hh; l[d] = f2b(v[d] - b2f(hh));
    }
    *(u16x4_t*)(xh + (size_t)i * 4) = h;
    *(u16x4_t*)(xl + (size_t)i * 4) = l;
  } else if (blk < 8192) {
    int i = (blk - 4096) * 256 + tid;
    f32x4_t v = *(const f32x4_t*)(mem + (size_t)i * 4);
    u16x4_t o;
    o[0] = f2b(v[0]); o[1] = f2b(v[1]); o[2] = f2b(v[2]); o[3] = f2b(v[3]);
    *(u16x4_t*)(memb + (size_t)i * 4) = o;
  } else if (blk < 8512) {
    int i = (blk - 8192) * 256 + tid;          // 0..81919
    unsigned c0, c1, o0, o1;
    tf2x32(0u, 42u, 0u, 1u, c0, c1);           // k2 = second split child
    tf2x32(c0, c1, 0u, (unsigned)i, o0, o1);
    idx[i] = (int)((o0 ^ o1) & 2047u);
  } else {
    int i = (blk - 8512) * 256 + tid;          // 0..4095
    if (i < 1024) biasqk[i] = sbq[i];
    else if (i < 2048) biasqk[i] = sbk[i - 1024];
    else if (i < 3072) cbkv[i - 2048] = cbk[i - 2048];
    else cbkv[i - 2048] = cbv[i - 3072];
  }
}

struct PrepW {
  const float* s2[2]; u16* dh2[2]; u16* dl2[2];
  const float* s6[6]; u16* d6[6];
  const float* W1; u16* W1T; const float* W2; u16* W2T;
};
__global__ __launch_bounds__(256)
void prep_weights(PrepW p) {
  __shared__ float t[64][65];
  int j = blockIdx.x;
  int c = threadIdx.x & 63, r4 = threadIdx.x >> 6;
  const float* in; u16* oh; u16* ol = nullptr;
  int K, N, k0, n0;
  if (j < 512) {
    int m = j >> 8, jj = j & 255;
    in = p.s2[m]; oh = p.dh2[m]; ol = p.dl2[m];
    K = 1024; N = 1024; n0 = (jj & 15) * 64; k0 = (jj >> 4) * 64;
  } else if (j < 2048) {
    int m = (j - 512) >> 8, jj = (j - 512) & 255;
    in = p.s6[m]; oh = p.d6[m];
    K = 1024; N = 1024; n0 = (jj & 15) * 64; k0 = (jj >> 4) * 64;
  } else if (j < 3072) {
    int jj = j - 2048;
    in = p.W1; oh = p.W1T;
    K = 1024; N = 4096; n0 = (jj & 63) * 64; k0 = (jj >> 6) * 64;
  } else {
    int jj = j - 3072;
    in = p.W2; oh = p.W2T;
    K = 4096; N = 1024; n0 = (jj & 15) * 64; k0 = (jj >> 4) * 64;
  }
#pragma unroll
  for (int i = 0; i < 16; ++i) {
    int r = r4 * 16 + i;
    t[r][c] = in[(size_t)(k0 + r) * N + n0 + c];
  }
  __syncthreads();
#pragma unroll
  for (int i = 0; i < 16; ++i) {
    int r = r4 * 16 + i;
    float f = t[c][r];
    u16 h = f2b(f);
    oh[(size_t)(n0 + r) * K + k0 + c] = h;
    if (ol) ol[(size_t)(n0 + r) * K + k0 + c] = f2b(f - b2f(h));
  }
}

// ---------------------------------------------------------------- bf16 GEMM
template<int NF>
__global__ __launch_bounds__(256)
void gemm_bf(const u16* __restrict__ A, const u16* __restrict__ Bt,
             const float* __restrict__ bias, float* __restrict__ Cf,
             u16* __restrict__ Cb, int M, int N, int K, int relu) {
  __shared__ __align__(16) u16 sA[2][128 * 32];
  __shared__ __align__(16) u16 sB[2][NF * 32 * 32];
  const int tid = threadIdx.x;
  const int wave = tid >> 6, lane = tid & 63;
  const int m0 = blockIdx.x * 128, n0 = blockIdx.y * (NF * 32);
  const int wr = (wave >> 1) * 64, wc = (wave & 1) * (NF * 16);
  const int lr = lane & 15, kg = lane >> 4;
  const int wv = __builtin_amdgcn_readfirstlane(wave);

  int rowA[2], c8A[2];
#pragma unroll
  for (int rep = 0; rep < 2; ++rep) {
    int P = (rep * 256 + tid) << 4;
    int L = P ^ (((P >> 7) & 3) << 4);
    rowA[rep] = L >> 6; c8A[rep] = (L >> 4) & 3;
  }
  int rowB[NF / 2], c8B[NF / 2];
#pragma unroll
  for (int rep = 0; rep < NF / 2; ++rep) {
    int P = (rep * 256 + tid) << 4;
    int L = P ^ (((P >> 7) & 3) << 4);
    rowB[rep] = L >> 6; c8B[rep] = (L >> 4) & 3;
  }

  f32x4_t acc[4][NF];
#pragma unroll
  for (int i = 0; i < 4; ++i)
#pragma unroll
    for (int j = 0; j < NF; ++j) acc[i][j] = f32x4_t{0.f, 0.f, 0.f, 0.f};

  auto STAGE = [&](int buf, int k0) {
#pragma unroll
    for (int rep = 0; rep < 2; ++rep)
      GLD16(A + (size_t)(m0 + rowA[rep]) * K + k0 + c8A[rep] * 8,
            &sA[buf][(rep * 256 + wv * 64) * 8]);
#pragma unroll
    for (int rep = 0; rep < NF / 2; ++rep)
      GLD16(Bt + (size_t)(n0 + rowB[rep]) * K + k0 + c8B[rep] * 8,
            &sB[buf][(rep * 256 + wv * 64) * 8]);
  };

  const int nk = K >> 5;
  STAGE(0, 0);
  __syncthreads();
  for (int t = 0; t < nk; ++t) {
    const int cur = t & 1;
    if (t + 1 < nk) STAGE(cur ^ 1, (t + 1) << 5);
    u16x8_t a8[4], b8[NF];
#pragma unroll
    for (int mi = 0; mi < 4; ++mi) {
      int La = (wr + mi * 16 + lr) * 64 + kg * 16;
      a8[mi] = *(const u16x8_t*)((const char*)sA[cur] + (La ^ (((La >> 7) & 3) << 4)));
    }
#pragma unroll
    for (int ni = 0; ni < NF; ++ni) {
      int Lb = (wc + ni * 16 + lr) * 64 + kg * 16;
      b8[ni] = *(const u16x8_t*)((const char*)sB[cur] + (Lb ^ (((Lb >> 7) & 3) << 4)));
    }
#pragma unroll
    for (int mi = 0; mi < 4; ++mi)
#pragma unroll
      for (int ni = 0; ni < NF; ++ni)
        acc[mi][ni] = mfma_bf16(a8[mi], b8[ni], acc[mi][ni]);
    __syncthreads();
  }
#pragma unroll
  for (int ni = 0; ni < NF; ++ni) {
    int col = n0 + wc + ni * 16 + lr;
    float bc = bias[col];
#pragma unroll
    for (int mi = 0; mi < 4; ++mi)
#pragma unroll
      for (int r = 0; r < 4; ++r) {
        int row = m0 + wr + mi * 16 + kg * 4 + r;
        float vv = acc[mi][ni][r] + bc;
        if (relu) vv = fmaxf(vv, 0.f);
        if (Cf) Cf[(size_t)row * N + col] = vv;
        if (Cb) Cb[(size_t)row * N + col] = f2b(vv);
      }
  }
}

// K-split GEMM: blockIdx.z picks K-half; z=0 adds bias, writes C0; z=1 writes C1.
template<int NF>
__global__ __launch_bounds__(256)
void gemm_ks(const u16* __restrict__ A, const u16* __restrict__ Bt,
             const float* __restrict__ bias, float* __restrict__ C0,
             float* __restrict__ C1, int M, int N, int K) {
  __shared__ __align__(16) u16 sA[2][128 * 32];
  __shared__ __align__(16) u16 sB[2][NF * 32 * 32];
  const int tid = threadIdx.x;
  const int wave = tid >> 6, lane = tid & 63;
  const int m0 = blockIdx.x * 128, n0 = blockIdx.y * (NF * 32);
  const int zz = blockIdx.z;
  const int Kh = K >> 1;
  const u16* Ab = A + (size_t)zz * Kh;
  const u16* Bb = Bt + (size_t)zz * Kh;
  float* Cf = zz ? C1 : C0;
  const int wr = (wave >> 1) * 64, wc = (wave & 1) * (NF * 16);
  const int lr = lane & 15, kg = lane >> 4;
  const int wv = __builtin_amdgcn_readfirstlane(wave);

  int rowA[2], c8A[2];
#pragma unroll
  for (int rep = 0; rep < 2; ++rep) {
    int P = (rep * 256 + tid) << 4;
    int L = P ^ (((P >> 7) & 3) << 4);
    rowA[rep] = L >> 6; c8A[rep] = (L >> 4) & 3;
  }
  int rowB[NF / 2], c8B[NF / 2];
#pragma unroll
  for (int rep = 0; rep < NF / 2; ++rep) {
    int P = (rep * 256 + tid) << 4;
    int L = P ^ (((P >> 7) & 3) << 4);
    rowB[rep] = L >> 6; c8B[rep] = (L >> 4) & 3;
  }

  f32x4_t acc[4][NF];
#pragma unroll
  for (int i = 0; i < 4; ++i)
#pragma unroll
    for (int j = 0; j < NF; ++j) acc[i][j] = f32x4_t{0.f, 0.f, 0.f, 0.f};

  auto STAGE = [&](int buf, int k0) {
#pragma unroll
    for (int rep = 0; rep < 2; ++rep)
      GLD16(Ab + (size_t)(m0 + rowA[rep]) * K + k0 + c8A[rep] * 8,
            &sA[buf][(rep * 256 + wv * 64) * 8]);
#pragma unroll
    for (int rep = 0; rep < NF / 2; ++rep)
      GLD16(Bb + (size_t)(n0 + rowB[rep]) * K + k0 + c8B[rep] * 8,
            &sB[buf][(rep * 256 + wv * 64) * 8]);
  };

  const int nk = Kh >> 5;
  STAGE(0, 0);
  __syncthreads();
  for (int t = 0; t < nk; ++t) {
    const int cur = t & 1;
    if (t + 1 < nk) STAGE(cur ^ 1, (t + 1) << 5);
    u16x8_t a8[4], b8[NF];
#pragma unroll
    for (int mi = 0; mi < 4; ++mi) {
      int La = (wr + mi * 16 + lr) * 64 + kg * 16;
      a8[mi] = *(const u16x8_t*)((const char*)sA[cur] + (La ^ (((La >> 7) & 3) << 4)));
    }
#pragma unroll
    for (int ni = 0; ni < NF; ++ni) {
      int Lb = (wc + ni * 16 + lr) * 64 + kg * 16;
      b8[ni] = *(const u16x8_t*)((const char*)sB[cur] + (Lb ^ (((Lb >> 7) & 3) << 4)));
    }
#pragma unroll
    for (int mi = 0; mi < 4; ++mi)
#pragma unroll
      for (int ni = 0; ni < NF; ++ni)
        acc[mi][ni] = mfma_bf16(a8[mi], b8[ni], acc[mi][ni]);
    __syncthreads();
  }
#pragma unroll
  for (int ni = 0; ni < NF; ++ni) {
    int col = n0 + wc + ni * 16 + lr;
    float bc = (zz == 0) ? bias[col] : 0.f;
#pragma unroll
    for (int mi = 0; mi < 4; ++mi)
#pragma unroll
      for (int r = 0; r < 4; ++r) {
        int row = m0 + wr + mi * 16 + kg * 4 + r;
        Cf[(size_t)row * N + col] = acc[mi][ni][r] + bc;
      }
  }
}

// 3-term split GEMM (f32-equivalent: hi*hi + hi*lo + lo*hi)
template<int NF>
__global__ __launch_bounds__(256)
void gemm4_bf(const u16* __restrict__ Ah, const u16* __restrict__ Al,
              const u16* __restrict__ Bh, const u16* __restrict__ Bl,
              const float* __restrict__ bias, float* __restrict__ Cf,
              int M, int N, int K) {
  __shared__ __align__(16) u16 sAh[2][128 * 32];
  __shared__ __align__(16) u16 sAl[2][128 * 32];
  __shared__ __align__(16) u16 sBh[2][NF * 32 * 32];
  __shared__ __align__(16) u16 sBl[2][NF * 32 * 32];
  const int tid = threadIdx.x;
  const int wave = tid >> 6, lane = tid & 63;
  const int m0 = blockIdx.x * 128, n0 = blockIdx.y * (NF * 32);
  const int wr = (wave >> 1) * 64, wc = (wave & 1) * (NF * 16);
  const int lr = lane & 15, kg = lane >> 4;
  const int wv = __builtin_amdgcn_readfirstlane(wave);

  int rowA[2], c8A[2];
#pragma unroll
  for (int rep = 0; rep < 2; ++rep) {
    int P = (rep * 256 + tid) << 4;
    int L = P ^ (((P >> 7) & 3) << 4);
    rowA[rep] = L >> 6; c8A[rep] = (L >> 4) & 3;
  }
  int rowB[NF / 2], c8B[NF / 2];
#pragma unroll
  for (int rep = 0; rep < NF / 2; ++rep) {
    int P = (rep * 256 + tid) << 4;
    int L = P ^ (((P >> 7) & 3) << 4);
    rowB[rep] = L >> 6; c8B[rep] = (L >> 4) & 3;
  }

  f32x4_t acc[4][NF];
#pragma unroll
  for (int i = 0; i < 4; ++i)
#pragma unroll
    for (int j = 0; j < NF; ++j) acc[i][j] = f32x4_t{0.f, 0.f, 0.f, 0.f};

  auto STAGE = [&](int buf, int k0) {
#pragma unroll
    for (int rep = 0; rep < 2; ++rep) {
      GLD16(Ah + (size_t)(m0 + rowA[rep]) * K + k0 + c8A[rep] * 8,
            &sAh[buf][(rep * 256 + wv * 64) * 8]);
      GLD16(Al + (size_t)(m0 + rowA[rep]) * K + k0 + c8A[rep] * 8,
            &sAl[buf][(rep * 256 + wv * 64) * 8]);
    }
#pragma unroll
    for (int rep = 0; rep < NF / 2; ++rep) {
      GLD16(Bh + (size_t)(n0 + rowB[rep]) * K + k0 + c8B[rep] * 8,
            &sBh[buf][(rep * 256 + wv * 64) * 8]);
      GLD16(Bl + (size_t)(n0 + rowB[rep]) * K + k0 + c8B[rep] * 8,
            &sBl[buf][(rep * 256 + wv * 64) * 8]);
    }
  };

  const int nk = K >> 5;
  STAGE(0, 0);
  __syncthreads();
  for (int t = 0; t < nk; ++t) {
    const int cur = t & 1;
    if (t + 1 < nk) STAGE(cur ^ 1, (t + 1) << 5);
    u16x8_t ah[4], al[4], bh[NF], bl[NF];
#pragma unroll
    for (int mi = 0; mi < 4; ++mi) {
      int La = (wr + mi * 16 + lr) * 64 + kg * 16;
      int off = La ^ (((La >> 7) & 3) << 4);
      ah[mi] = *(const u16x8_t*)((const char*)sAh[cur] + off);
      al[mi] = *(const u16x8_t*)((const char*)sAl[cur] + off);
    }
#pragma unroll
    for (int ni = 0; ni < NF; ++ni) {
      int Lb = (wc + ni * 16 + lr) * 64 + kg * 16;
      int off = Lb ^ (((Lb >> 7) & 3) << 4);
      bh[ni] = *(const u16x8_t*)((const char*)sBh[cur] + off);
      bl[ni] = *(const u16x8_t*)((const char*)sBl[cur] + off);
    }
#pragma unroll
    for (int mi = 0; mi < 4; ++mi)
#pragma unroll
      for (int ni = 0; ni < NF; ++ni) {
        acc[mi][ni] = mfma_bf16(ah[mi], bh[ni], acc[mi][ni]);
        acc[mi][ni] = mfma_bf16(ah[mi], bl[ni], acc[mi][ni]);
        acc[mi][ni] = mfma_bf16(al[mi], bh[ni], acc[mi][ni]);
      }
    __syncthreads();
  }
#pragma unroll
  for (int ni = 0; ni < NF; ++ni) {
    int col = n0 + wc + ni * 16 + lr;
    float bc = bias[col];
#pragma unroll
    for (int mi = 0; mi < 4; ++mi)
#pragma unroll
      for (int r = 0; r < 4; ++r) {
        int row = m0 + wr + mi * 16 + kg * 4 + r;
        Cf[(size_t)row * N + col] = acc[mi][ni][r] + bc;
      }
  }
}

// ---------------------------------------------------------------- ProbSparse
__global__ __launch_bounds__(256)
void probM_kernel(const float* __restrict__ qk, const int* __restrict__ idx,
                  float* __restrict__ Mv) {
  int blk = blockIdx.x;                        // 0..1023
  int xcd = blk & 7, j = blk >> 3;             // j: 0..127
  int b = xcd >> 2;
  int part = (xcd & 3) * 128 + j;              // 0..511
  int l = part * 4 + (threadIdx.x >> 6);
  int lane = threadIdx.x & 63;
  const float* qrow = qk + ((size_t)b * SEQ + l) * 2048 + lane * 16;
  f32x4_t qv0 = *(const f32x4_t*)(qrow);
  f32x4_t qv1 = *(const f32x4_t*)(qrow + 4);
  f32x4_t qv2 = *(const f32x4_t*)(qrow + 8);
  f32x4_t qv3 = *(const f32x4_t*)(qrow + 12);
  const int* ip = idx + l * NTOP;
  const float* kbase = qk + (size_t)b * SEQ * 2048 + 1024 + lane * 16;
  float mmax = -3.0e38f, msum = 0.f;
  for (int pass = 0; pass < 4; ++pass) {
    int lo = pass << 9;
#pragma unroll 4
    for (int u = 0; u < NTOP; ++u) {
      int ki = ip[u];
      if ((unsigned)(ki - lo) < 512u) {        // wave-uniform branch
        const float* kr = kbase + (size_t)ki * 2048;
        f32x4_t k0 = *(const f32x4_t*)(kr);
        f32x4_t k1 = *(const f32x4_t*)(kr + 4);
        f32x4_t k2 = *(const f32x4_t*)(kr + 8);
        f32x4_t k3 = *(const f32x4_t*)(kr + 12);
        float p = qv0[0] * k0[0] + qv0[1] * k0[1] + qv0[2] * k0[2] + qv0[3] * k0[3]
                + qv1[0] * k1[0] + qv1[1] * k1[1] + qv1[2] * k1[2] + qv1[3] * k1[3]
                + qv2[0] * k2[0] + qv2[1] * k2[1] + qv2[2] * k2[2] + qv2[3] * k2[3]
                + qv3[0] * k3[0] + qv3[1] * k3[1] + qv3[2] * k3[2] + qv3[3] * k3[3];
        p += __shfl_xor(p, 1);
        p += __shfl_xor(p, 2);
        mmax = fmaxf(mmax, p);
        msum += p;
      }
    }
  }
  if ((lane & 3) == 0) {
    int hh = lane >> 2;
    Mv[((size_t)b * NHEADS + hh) * SEQ + l] = mmax - msum * (1.f / 2048.f);
  }
}

// register-resident iterative top-40
__global__ __launch_bounds__(256)
void topk_kernel(const float* __restrict__ Mv, int* __restrict__ Mtop) {
  int bh = blockIdx.x;
  int tid = threadIdx.x;
  int lane = tid & 63, wv = tid >> 6;
  float v8[8];
#pragma unroll
  for (int j = 0; j < 8; ++j) v8[j] = Mv[bh * 2048 + j * 256 + tid];
  __shared__ float wrv[4];
  __shared__ int wri[4];
  __shared__ int winner;
  for (int it = 0; it < NTOP; ++it) {
    float best = v8[0];
    int bj = 0;
#pragma unroll
    for (int j = 1; j < 8; ++j)
      if (v8[j] > best) { best = v8[j]; bj = j; }
    int bi = bj * 256 + tid;
#pragma unroll
    for (int m = 1; m < 64; m <<= 1) {
      float ov = __shfl_xor(best, m);
      int oi = __shfl_xor(bi, m);
      if (ov > best || (ov == best && oi < bi)) { best = ov; bi = oi; }
    }
    if (lane == 0) { wrv[wv] = best; wri[wv] = bi; }
    __syncthreads();
    if (tid == 0) {
      float bv = wrv[0]; int bbi = wri[0];
#pragma unroll
      for (int t = 1; t < 4; ++t)
        if (wrv[t] > bv || (wrv[t] == bv && wri[t] < bbi)) { bv = wrv[t]; bbi = wri[t]; }
      Mtop[bh * NTOP + it] = bbi;
      winner = bbi;
    }
    __syncthreads();
    int w = winner;
#pragma unroll
    for (int j = 0; j < 8; ++j)
      if ((w >> 8) == j && (w & 255) == tid) v8[j] = -3.4e38f;
  }
}

// ---------------------------------------------------------------- kv pack (self)
__global__ __launch_bounds__(256)
void kvpack_self(const float* __restrict__ qk, const u16* __restrict__ vbf,
                 u16* __restrict__ kpack, u16* __restrict__ vpack) {
  int bh = blockIdx.x, ch = blockIdx.y;
  int b = bh >> 4, hh = bh & 15;
  int tid = threadIdx.x;
  __shared__ u16 vt[64][80];
#pragma unroll
  for (int rep = 0; rep < 2; ++rep) {
    int u = rep * 256 + tid;
    int key = u >> 3, c = u & 7;
    const float* ksrc = qk + ((size_t)(b * SEQ + ch * 64 + key)) * 2048 + 1024 + hh * 64 + c * 8;
    f32x4_t k0 = *(const f32x4_t*)ksrc;
    f32x4_t k1 = *(const f32x4_t*)(ksrc + 4);
    u16x8_t d;
    d[0] = f2bf(k0[0]); d[1] = f2bf(k0[1]); d[2] = f2bf(k0[2]); d[3] = f2bf(k0[3]);
    d[4] = f2bf(k1[0]); d[5] = f2bf(k1[1]); d[6] = f2bf(k1[2]); d[7] = f2bf(k1[3]);
    int slot = (key & 3) | (((key >> 3) & 1) << 2);
    *(u16x8_t*)(kpack + ((size_t)bh * SEQ + ch * 64 + key) * 64 + ((c ^ slot) * 8)) = d;
    u16x8_t dv = *(const u16x8_t*)(vbf + ((size_t)(b * SEQ + ch * 64 + key)) * 1024 + hh * 64 + c * 8);
    *(u16x8_t*)(&vt[key][c * 8]) = dv;
  }
  __syncthreads();
#pragma unroll
  for (int rep = 0; rep < 2; ++rep) {
    int u = rep * 256 + tid;
    int e = u >> 3, c = u & 7;
    int kb = (c ^ (e & 7)) * 8;
    u16x8_t d;
#pragma unroll
    for (int j = 0; j < 8; ++j) d[j] = vt[kb + j][e];
    *(u16x8_t*)(vpack + (((size_t)bh * 32 + ch) * 64 + e) * 64 + c * 8) = d;
  }
}

// ---------------------------------------------------------------- probAttn
__global__ __launch_bounds__(256)
void probAttn_kernel(const float* __restrict__ qk, const u16* __restrict__ kpack,
                     const u16* __restrict__ vpack, const int* __restrict__ Mtop,
                     float* __restrict__ Opart, float* __restrict__ ml) {
  const int bh = blockIdx.x, b = bh >> 4, hh = bh & 15;
  const int split = blockIdx.y;                 // 0..7 (256 keys each)
  const int tid = threadIdx.x, wave = tid >> 6, lane = tid & 63;
  const int lr = lane & 15, kg = lane >> 4;
  const int wv = __builtin_amdgcn_readfirstlane(wave);
  __shared__ __align__(16) u16 Qs[48 * 64];
  __shared__ __align__(16) u16 Kt[2][64 * 64];
  __shared__ __align__(16) u16 Vt[2][64 * 64];

#pragma unroll
  for (int rep = 0; rep < 3; ++rep) {
    int j = tid + 256 * rep;        // 0..767
    int row = j >> 4, c4 = j & 15;
    int qi = Mtop[bh * NTOP + (row < NTOP ? row : NTOP - 1)];
    f32x4_t v4 = *(const f32x4_t*)(qk + ((size_t)b * SEQ + qi) * 2048 + hh * EHEAD + c4 * 4);
    u16x4_t b4;
    b4[0] = f2bf(v4[0] * QSCALE); b4[1] = f2bf(v4[1] * QSCALE);
    b4[2] = f2bf(v4[2] * QSCALE); b4[3] = f2bf(v4[3] * QSCALE);
    *(u16x4_t*)((char*)Qs + ((row * 128 + c4 * 8) ^ ((row & 7) << 4))) = b4;
  }

  const int qtile = (wave < 3) ? wave : 2;
  const int qrow_g = qtile * 16 + lr;
  const int iq = (qrow_g < NTOP) ? Mtop[bh * NTOP + qrow_g] : -1;

  int koffs[2][4], voffs[2][4], kbase16[4];
#pragma unroll
  for (int t4 = 0; t4 < 4; ++t4) {
    int arow = ((t4 >> 1) << 5) + ((lr >> 2) << 3) + ((t4 & 1) << 2) + (lr & 3);
    int slot = (arow & 3) | (((arow >> 3) & 1) << 2);
#pragma unroll
    for (int ks = 0; ks < 2; ++ks)
      koffs[ks][t4] = ((arow << 7) + (ks << 6) + (kg << 4)) ^ (slot << 4);
    kbase16[t4] = ((t4 >> 1) << 5) + (kg << 3) + ((t4 & 1) << 2);
  }
#pragma unroll
  for (int ne = 0; ne < 4; ++ne) {
    int e = ne * 16 + lr;
#pragma unroll
    for (int ks2 = 0; ks2 < 2; ++ks2)
      voffs[ks2][ne] = ((e << 7) + (ks2 << 6) + (kg << 4)) ^ ((e & 7) << 4);
  }
  const int maskbase = split * 256 - iq;

  const char* kgl = (const char*)kpack + (size_t)bh * SEQ * 128 + (size_t)split * 4 * 8192;
  const char* vgl = (const char*)vpack + (size_t)bh * 32 * 8192 + (size_t)split * 4 * 8192;
  auto STAGE = [&](int buf, int t) {
    GLD16(kgl + (size_t)t * 8192 + wv * 2048 + lane * 16, (char*)Kt[buf] + wv * 2048);
    GLD16(kgl + (size_t)t * 8192 + wv * 2048 + 1024 + lane * 16, (char*)Kt[buf] + wv * 2048 + 1024);
    GLD16(vgl + (size_t)t * 8192 + wv * 2048 + lane * 16, (char*)Vt[buf] + wv * 2048);
    GLD16(vgl + (size_t)t * 8192 + wv * 2048 + 1024 + lane * 16, (char*)Vt[buf] + wv * 2048 + 1024);
  };

  STAGE(0, 0);
  __syncthreads();

  u16x8_t bq[2];
  {
    int qrow = qtile * 16 + lr;
#pragma unroll
    for (int ks = 0; ks < 2; ++ks)
      bq[ks] = *(u16x8_t*)((char*)Qs + ((qrow * 128 + ks * 64 + kg * 16) ^ ((qrow & 7) << 4)));
  }

  f32x4_t oacc[4];
#pragma unroll
  for (int i = 0; i < 4; ++i) oacc[i] = f32x4_t{0.f, 0.f, 0.f, 0.f};
  float lsum = 0.f;

  for (int t = 0; t < 4; ++t) {
    const int cur = t & 1;
    if (t + 1 < 4) STAGE(cur ^ 1, t + 1);
    const char* kb = (const char*)Kt + cur * 8192;
    const char* vb = (const char*)Vt + cur * 8192;
    f32x4_t s[4];
#pragma unroll
    for (int i = 0; i < 4; ++i) s[i] = f32x4_t{-FIXM, -FIXM, -FIXM, -FIXM};
#pragma unroll
    for (int ks = 0; ks < 2; ++ks)
#pragma unroll
      for (int t4 = 0; t4 < 4; ++t4) {
        u16x8_t ak = *(const u16x8_t*)(kb + koffs[ks][t4]);
        s[t4] = mfma_bf16(ak, bq[ks], s[t4]);
      }
    const int mb = t * 64 + maskbase;
#pragma unroll
    for (int t4 = 0; t4 < 4; ++t4)
#pragma unroll
      for (int r = 0; r < 4; ++r)
        if (mb + kbase16[t4] + r > 0) s[t4][r] = -1e9f;
#pragma unroll
    for (int t4 = 0; t4 < 4; ++t4)
#pragma unroll
      for (int r = 0; r < 4; ++r) {
        float p = exp2f(s[t4][r]);
        s[t4][r] = p; lsum += p;
      }
#pragma unroll
    for (int ks2 = 0; ks2 < 2; ++ks2) {
      u16x8_t pa;
#pragma unroll
      for (int j = 0; j < 4; ++j) {
        pa[j] = f2bf(s[2 * ks2][j]);
        pa[4 + j] = f2bf(s[2 * ks2 + 1][j]);
      }
#pragma unroll
      for (int ne = 0; ne < 4; ++ne) {
        u16x8_t bv = *(const u16x8_t*)(vb + voffs[ks2][ne]);
        oacc[ne] = mfma_bf16(pa, bv, oacc[ne]);
      }
    }
    __syncthreads();
  }

  lsum += __shfl_xor(lsum, 16);
  lsum += __shfl_xor(lsum, 32);

  if (wave < 3) {
    float* ob = Opart + (((size_t)(bh * 8 + split)) * 48 + qtile * 16) * 64;
#pragma unroll
    for (int ne = 0; ne < 4; ++ne)
#pragma unroll
      for (int r = 0; r < 4; ++r)
        ob[(size_t)(kg * 4 + r) * 64 + ne * 16 + lr] = oacc[ne][r];
    if (kg == 0)
      ml[((size_t)(bh * 8 + split)) * 48 + qtile * 16 + lr] = lsum;
  }
}

__global__ __launch_bounds__(64)
void probCombine_kernel(const float* __restrict__ Opart, const float* __restrict__ ml,
                        const int* __restrict__ Mtop, u16* __restrict__ ctxb) {
  int bh = blockIdx.x / NTOP, q = blockIdx.x % NTOP;
  int e = threadIdx.x;
  int b = bh >> 4, hh = bh & 15;
  float lstar = 0.f, acc = 0.f;
#pragma unroll
  for (int s = 0; s < 8; ++s) {
    lstar += ml[((size_t)(bh * 8 + s)) * 48 + q];
    acc += Opart[(((size_t)(bh * 8 + s)) * 48 + q) * 64 + e];
  }
  int row = Mtop[bh * NTOP + q];
  ctxb[((size_t)b * SEQ + row) * DMODEL + hh * EHEAD + e] = f2bf(acc / lstar);
}

// ---------------------------------------------------------------- scans
__global__ __launch_bounds__(64)
void scanA_kernel(const u16* __restrict__ v, float* __restrict__ csum) {
  int bh = blockIdx.x, ch = blockIdx.y;
  int b = bh >> 4, hh = bh & 15, e = threadIdx.x;
  size_t base = ((size_t)b * SEQ + ch * 128) * DMODEL + hh * EHEAD + e;
  float run = 0.f;
  for (int i = 0; i < 128; ++i) run += b2f(v[base + (size_t)i * DMODEL]);
  csum[(bh * 16 + ch) * 64 + e] = run;
}
__global__ __launch_bounds__(64)
void scanB_kernel(const u16* __restrict__ v, const float* __restrict__ csum,
                  u16* __restrict__ ctxb) {
  int bh = blockIdx.x, ch = blockIdx.y;
  int b = bh >> 4, hh = bh & 15, e = threadIdx.x;
  float run = 0.f;
  for (int cc = 0; cc < ch; ++cc) run += csum[(bh * 16 + cc) * 64 + e];
  size_t base = ((size_t)b * SEQ + ch * 128) * DMODEL + hh * EHEAD + e;
  for (int i = 0; i < 128; ++i) {
    run += b2f(v[base + (size_t)i * DMODEL]);
    ctxb[base + (size_t)i * DMODEL] = f2bf(run);
  }
}

// ---------------------------------------------------------------- kv pack (cross)
__global__ __launch_bounds__(256)
void kvpack_kernel(const u16* __restrict__ kv, u16* __restrict__ kpack,
                   u16* __restrict__ vpack) {
  int bh = blockIdx.x, ch = blockIdx.y;
  int b = bh >> 4, hh = bh & 15;
  int tid = threadIdx.x;
  __shared__ u16 vt[64][80];
#pragma unroll
  for (int rep = 0; rep < 2; ++rep) {
    int u = rep * 256 + tid;
    int key = u >> 3, c = u & 7;
    u16x8_t d = *(const u16x8_t*)(kv + ((size_t)(b * SEQ + ch * 64 + key)) * 2048 + hh * 64 + c * 8);
    int slot = (key & 3) | (((key >> 3) & 1) << 2);
    *(u16x8_t*)(kpack + ((size_t)bh * SEQ + ch * 64 + key) * 64 + ((c ^ slot) * 8)) = d;
    u16x8_t dv = *(const u16x8_t*)(kv + ((size_t)(b * SEQ + ch * 64 + key)) * 2048 + 1024 + hh * 64 + c * 8);
    *(u16x8_t*)(&vt[key][c * 8]) = dv;
  }
  __syncthreads();
#pragma unroll
  for (int rep = 0; rep < 2; ++rep) {
    int u = rep * 256 + tid;
    int e = u >> 3, c = u & 7;
    int kb = (c ^ (e & 7)) * 8;
    u16x8_t d;
#pragma unroll
    for (int j = 0; j < 8; ++j) d[j] = vt[kb + j][e];
    *(u16x8_t*)(vpack + (((size_t)bh * 32 + ch) * 64 + e) * 64 + c * 8) = d;
  }
}

// ---------------------------------------------------------------- cross attn
// 128-q tile, 8 waves, 2-way key split. Q = q2a + q2b (K-split partials).
__global__ __launch_bounds__(512)
void cross_attn_kernel(const float* __restrict__ q2a, const float* __restrict__ q2b,
                       const u16* __restrict__ kpack, const u16* __restrict__ vpack,
                       u16* __restrict__ Opb, float* __restrict__ lsb) {
  const int bh = blockIdx.x, b = bh >> 4, hh = bh & 15;
  const int qt0 = blockIdx.y * 128;
  const int split = blockIdx.z;               // 0..1 (1024 keys each)
  const int tid = threadIdx.x, wave = tid >> 6, lane = tid & 63;
  const int lr = lane & 15, kg = lane >> 4;
  const int wv = __builtin_amdgcn_readfirstlane(wave);
  __shared__ __align__(16) u16 Qs[128 * 64];
  __shared__ __align__(16) u16 Kt[2][64 * 64];
  __shared__ __align__(16) u16 Vt[2][64 * 64];

#pragma unroll
  for (int i = 0; i < 4; ++i) {
    int j = tid + 512 * i;
    int row = j >> 4, c4 = j & 15;
    size_t qoff = ((size_t)b * SEQ + qt0 + row) * DMODEL + hh * EHEAD + c4 * 4;
    f32x4_t v4 = *(const f32x4_t*)(q2a + qoff);
    f32x4_t v4b = *(const f32x4_t*)(q2b + qoff);
    u16x4_t b4;
    b4[0] = f2bf((v4[0] + v4b[0]) * QSCALE); b4[1] = f2bf((v4[1] + v4b[1]) * QSCALE);
    b4[2] = f2bf((v4[2] + v4b[2]) * QSCALE); b4[3] = f2bf((v4[3] + v4b[3]) * QSCALE);
    *(u16x4_t*)((char*)Qs + ((row * 128 + c4 * 8) ^ ((row & 7) << 4))) = b4;
  }

  int koffs[2][4], voffs[2][4];
#pragma unroll
  for (int t4 = 0; t4 < 4; ++t4) {
    int arow = ((t4 >> 1) << 5) + ((lr >> 2) << 3) + ((t4 & 1) << 2) + (lr & 3);
    int slot = (arow & 3) | (((arow >> 3) & 1) << 2);
#pragma unroll
    for (int ks = 0; ks < 2; ++ks)
      koffs[ks][t4] = ((arow << 7) + (ks << 6) + (kg << 4)) ^ (slot << 4);
  }
#pragma unroll
  for (int ne = 0; ne < 4; ++ne) {
    int e = ne * 16 + lr;
#pragma unroll
    for (int ks2 = 0; ks2 < 2; ++ks2)
      voffs[ks2][ne] = ((e << 7) + (ks2 << 6) + (kg << 4)) ^ ((e & 7) << 4);
  }

  const char* kgl = (const char*)kpack + (size_t)bh * SEQ * 128 + (size_t)split * 1024 * 128;
  const char* vgl = (const char*)vpack + (size_t)bh * 32 * 8192 + (size_t)split * 16 * 8192;
  auto STAGE = [&](int buf, int t) {
    GLD16(kgl + (size_t)t * 8192 + wv * 1024 + lane * 16, (char*)Kt[buf] + wv * 1024);
    GLD16(vgl + (size_t)t * 8192 + wv * 1024 + lane * 16, (char*)Vt[buf] + wv * 1024);
  };

  STAGE(0, 0);
  __syncthreads();

  u16x8_t bq[2];
  {
    int qrow = wave * 16 + lr;
#pragma unroll
    for (int ks = 0; ks < 2; ++ks)
      bq[ks] = *(u16x8_t*)((char*)Qs + ((qrow * 128 + ks * 64 + kg * 16) ^ ((qrow & 7) << 4)));
  }

  f32x4_t oacc[4];
#pragma unroll
  for (int i = 0; i < 4; ++i) oacc[i] = f32x4_t{0.f, 0.f, 0.f, 0.f};
  float lsum = 0.f;

  for (int t = 0; t < 16; ++t) {
    const int cur = t & 1;
    if (t + 1 < 16) STAGE(cur ^ 1, t + 1);
    const char* kb = (const char*)Kt + cur * 8192;
    const char* vb = (const char*)Vt + cur * 8192;
    f32x4_t s[4];
#pragma unroll
    for (int i = 0; i < 4; ++i) s[i] = f32x4_t{-FIXM, -FIXM, -FIXM, -FIXM};
#pragma unroll
    for (int ks = 0; ks < 2; ++ks)
#pragma unroll
      for (int t4 = 0; t4 < 4; ++t4) {
        u16x8_t ak = *(const u16x8_t*)(kb + koffs[ks][t4]);
        s[t4] = mfma_bf16(ak, bq[ks], s[t4]);
      }
#pragma unroll
    for (int t4 = 0; t4 < 4; ++t4)
#pragma unroll
      for (int r = 0; r < 4; ++r) {
        float p = exp2f(s[t4][r]);
        s[t4][r] = p; lsum += p;
      }
#pragma unroll
    for (int ks2 = 0; ks2 < 2; ++ks2) {
      u16x8_t pa;
#pragma unroll
      for (int j = 0; j < 4; ++j) {
        pa[j] = f2bf(s[2 * ks2][j]);
        pa[4 + j] = f2bf(s[2 * ks2 + 1][j]);
      }
#pragma unroll
      for (int ne = 0; ne < 4; ++ne) {
        u16x8_t bv = *(const u16x8_t*)(vb + voffs[ks2][ne]);
        oacc[ne] = mfma_bf16(pa, bv, oacc[ne]);
      }
    }
    __syncthreads();
  }

  lsum += __shfl_xor(lsum, 16);
  lsum += __shfl_xor(lsum, 32);

  size_t gbase = ((size_t)split * 32 + bh) * 2048 + qt0;
#pragma unroll
  for (int ne = 0; ne < 4; ++ne)
#pragma unroll
    for (int r = 0; r < 4; ++r) {
      int rowl = wave * 16 + kg * 4 + r;
      Opb[(gbase + rowl) * 64 + ne * 16 + lr] = f2bf(oacc[ne][r]);
    }
  if (kg == 0)
    lsb[gbase + wave * 16 + lr] = lsum;
}

// combine 2 key-split partials -> cab bf16 [B][SEQ][DMODEL]
__global__ __launch_bounds__(256)
void caCombine_kernel(const u16* __restrict__ Opb, const float* __restrict__ lsb,
                      u16* __restrict__ cab) {
  int i = blockIdx.x * 256 + threadIdx.x;     // 0..1048575, 4 elems each
  int base = i * 4;
  int g = base >> 6;                          // 0..65535 (bh*2048+row)
  int col = base & 63;
  u16x4_t p0 = *(const u16x4_t*)(Opb + (size_t)g * 64 + col);
  u16x4_t p1 = *(const u16x4_t*)(Opb + ((size_t)65536 + g) * 64 + col);
  float inv = 1.0f / (lsb[g] + lsb[65536 + g]);
  int bh = g >> 11, row = g & 2047;
  int b = bh >> 4, hh = bh & 15;
  u16x4_t o;
#pragma unroll
  for (int d = 0; d < 4; ++d)
    o[d] = f2bf((b2f(p0[d]) + b2f(p1[d])) * inv);
  *(u16x4_t*)(cab + ((size_t)(b * 2048 + row)) * 1024 + hh * 64 + col) = o;
}

// ---------------------------------------------------------------- layernorm
__global__ __launch_bounds__(256)
void ln_kernel(const float* __restrict__ x, const float* __restrict__ r,
               const float* __restrict__ g, const float* __restrict__ be,
               float* __restrict__ outf, u16* __restrict__ outb) {
  int row = blockIdx.x, tid = threadIdx.x;
  size_t base = (size_t)row * DMODEL;
  float v[4];
  float s = 0.f, sq = 0.f;
#pragma unroll
  for (int i = 0; i < 4; ++i) {
    int c = tid + i * 256;
    float t = x[base + c] + r[base + c];
    v[i] = t; s += t; sq += t * t;
  }
  __shared__ float rs[256], rq[256];
  rs[tid] = s; rq[tid] = sq;
  __syncthreads();
  for (int st = 128; st > 0; st >>= 1) {
    if (tid < st) { rs[tid] += rs[tid + st]; rq[tid] += rq[tid + st]; }
    __syncthreads();
  }
  float mean = rs[0] * (1.f / DMODEL);
  float var = rq[0] * (1.f / DMODEL) - mean * mean;
  float rstd = rsqrtf(var + 1e-5f);
#pragma unroll
  for (int i = 0; i < 4; ++i) {
    int c = tid + i * 256;
    float o = (v[i] - mean) * rstd * g[c] + be[c];
    if (outf) outf[base + c] = o;
    if (outb) outb[base + c] = f2bf(o);
  }
}

// 3-input layernorm: t = x + r0 + r1 (K-split GEMM partials)
__global__ __launch_bounds__(256)
void ln3_kernel(const float* __restrict__ x, const float* __restrict__ r0,
                const float* __restrict__ r1, const float* __restrict__ g,
                const float* __restrict__ be, float* __restrict__ outf,
                u16* __restrict__ outb) {
  int row = blockIdx.x, tid = threadIdx.x;
  size_t base = (size_t)row * DMODEL;
  float v[4];
  float s = 0.f, sq = 0.f;
#pragma unroll
  for (int i = 0; i < 4; ++i) {
    int c = tid + i * 256;
    float t = x[base + c] + r0[base + c] + r1[base + c];
    v[i] = t; s += t; sq += t * t;
  }
  __shared__ float rs[256], rq[256];
  rs[tid] = s; rq[tid] = sq;
  __syncthreads();
  for (int st = 128; st > 0; st >>= 1) {
    if (tid < st) { rs[tid] += rs[tid + st]; rq[tid] += rq[tid + st]; }
    __syncthreads();
  }
  float mean = rs[0] * (1.f / DMODEL);
  float var = rq[0] * (1.f / DMODEL) - mean * mean;
  float rstd = rsqrtf(var + 1e-5f);
#pragma unroll
  for (int i = 0; i < 4; ++i) {
    int c = tid + i * 256;
    float o = (v[i] - mean) * rstd * g[c] + be[c];
    if (outf) outf[base + c] = o;
    if (outb) outb[base + c] = f2bf(o);
  }
}

// ---------------------------------------------------------------- host side
static inline void gemm(const u16* A, const u16* Bt, const float* bias, float* Cf,
                        u16* Cb, int M, int N, int K, int relu, hipStream_t s,
                        int big = 0) {
  if (big)
    gemm_bf<4><<<dim3(M / 128, N / 128), 256, 0, s>>>(A, Bt, bias, Cf, Cb, M, N, K, relu);
  else
    gemm_bf<2><<<dim3(M / 128, N / 64), 256, 0, s>>>(A, Bt, bias, Cf, Cb, M, N, K, relu);
}
static inline void gemmks(const u16* A, const u16* Bt, const float* bias, float* C0,
                          float* C1, int M, int N, int K, hipStream_t s) {
  gemm_ks<4><<<dim3(M / 128, N / 128, 2), 256, 0, s>>>(A, Bt, bias, C0, C1, M, N, K);
}
static inline void gemm4(const u16* Ah, const u16* Al, const u16* Bh, const u16* Bl,
                         const float* bias, float* Cf, int M, int N, int K, hipStream_t s) {
  gemm4_bf<4><<<dim3(M / 128, N / 128), 256, 0, s>>>(Ah, Al, Bh, Bl, bias, Cf, M, N, K);
}

extern "C" void kernel_launch(void* const* d_in, const int* in_sizes, int n_in,
                              void* d_out, int out_size, void* d_ws, size_t ws_size,
                              hipStream_t stream) {
  const float* x   = (const float*)d_in[0];
  const float* mem = (const float*)d_in[1];
  const float* sWq = (const float*)d_in[2];  const float* sbq = (const float*)d_in[3];
  const float* sWk = (const float*)d_in[4];  const float* sbk = (const float*)d_in[5];
  const float* sWv = (const float*)d_in[6];  const float* sbv = (const float*)d_in[7];
  const float* sWo = (const float*)d_in[8];  const float* sbo = (const float*)d_in[9];
  const float* cWq = (const float*)d_in[10]; const float* cbq = (const float*)d_in[11];
  const float* cWk = (const float*)d_in[12]; const float* cbk = (const float*)d_in[13];
  const float* cWv = (const float*)d_in[14]; const float* cbv = (const float*)d_in[15];
  const float* cWo = (const float*)d_in[16]; const float* cbo = (const float*)d_in[17];
  const float* W1  = (const float*)d_in[18]; const float* b1  = (const float*)d_in[19];
  const float* W2  = (const float*)d_in[20]; const float* b2  = (const float*)d_in[21];
  const float* g1  = (const float*)d_in[22]; const float* be1 = (const float*)d_in[23];
  const float* g2  = (const float*)d_in[24]; const float* be2 = (const float*)d_in[25];
  const float* g3  = (const float*)d_in[26]; const float* be3 = (const float*)d_in[27];
  float* outp = (float*)d_out;
  char* ws = (char*)d_ws;
  const size_t MB = 1ull << 20;

  // ---- [0,2) MB: small buffers ----
  int*   idx    = (int*)(ws);
  float* Mv     = (float*)(ws + 0x60000);
  int*   Mtop   = (int*)(ws + 0xA0000);
  float* biasqk = (float*)(ws + 0x120000);
  float* cbkv   = (float*)(ws + 0x122000);
  float* csum   = (float*)(ws + 0x130000);   // 128KB

  // ---- [2,38) MB: weight transposes ----
  u16* WqkhT = (u16*)(ws + 2 * MB);    // [2,6)
  u16* WqklT = (u16*)(ws + 6 * MB);    // [6,10)
  u16* sWvT  = (u16*)(ws + 10 * MB);   // [10,12)
  u16* sWoT  = (u16*)(ws + 12 * MB);   // [12,14)
  u16* cWqT  = (u16*)(ws + 14 * MB);   // [14,16)
  u16* cWkvT = (u16*)(ws + 16 * MB);   // [16,20)
  u16* cWoT  = (u16*)(ws + 20 * MB);   // [20,22)
  u16* W1T   = (u16*)(ws + 22 * MB);   // [22,30)
  u16* W2T   = (u16*)(ws + 30 * MB);   // [30,38)

  // ---- activations (timeline-checked, no overlapping live ranges) ----
  u16*   xh    = (u16*)(ws + 38 * MB);     // [38,46)
  u16*   xl    = (u16*)(ws + 46 * MB);     // [46,54) dead after gemm4
  u16*   memb  = (u16*)(ws + 54 * MB);     // [54,62) dead after cross KV gemm
  float* qk    = (float*)(ws + 62 * MB);   // [62,94) f32, dead after probAttn
  u16*   vbf   = (u16*)(ws + 94 * MB);     // [94,102) dead after scans
  u16*   kpks  = (u16*)(ws + 102 * MB);    // [102,110) dead after probAttn
  u16*   vpks  = (u16*)(ws + 46 * MB);     // over xl, dead after probAttn
  float* Opart = (float*)(ws + 110 * MB);  // [110,113) dead after probCombine
  float* mlbuf = (float*)(ws + 113 * MB);  // 49KB
  u16*   ctxb  = (u16*)(ws + 78 * MB);     // [78,86) inside dead qk; dead after sWo gemmks
  float* sa0   = (float*)(ws + 94 * MB);   // [94,110) over vbf+kpks (dead)
  float* sa1   = (float*)(ws + 62 * MB);   // [62,78) over dead qk lower half
  float* x1    = (float*)(ws + 38 * MB);   // [38,54) over xh+xl/vpks (dead); live to ln3#2
  u16*   x1b   = (u16*)(ws + 78 * MB);     // over ctxb (dead); dead after cWq gemmks
  float* q20   = (float*)(ws + 62 * MB);   // [62,78) over sa1 (dead after ln3#1)
  float* q21   = (float*)(ws + 86 * MB);   // [86,102) over qk-upper/sa0 (dead)
  u16*   kv2b  = (u16*)(ws + 102 * MB);    // [102,118); dead after kvpack
  u16*   kpk   = (u16*)(ws + 2 * MB);      // [2,10) over WqkhT/WqklT (dead)
  u16*   vpk   = (u16*)(ws + 10 * MB);     // [10,18) over sWvT/sWoT/cWqT/cWkvT-lo (all dead by kvpack)
  u16*   Opb   = (u16*)(ws + 102 * MB);    // [102,118) over kv2b (dead after kvpack)
  float* lsb   = (float*)(ws + 18 * MB);   // [18,18.5) over cWkvT-hi (dead after KV gemm)
  u16*   cab   = (u16*)(ws + 54 * MB);     // [54,62) over memb (dead)
  float* ca0   = (float*)(ws + 62 * MB);   // [62,78) over q20 (dead after cross_attn)
  float* ca1   = (float*)(ws + 86 * MB);   // [86,102) over q21 (dead)
  float* x2    = (float*)(ws + 102 * MB);  // [102,118) over Opb (dead after caCombine)
  u16*   x2b   = (u16*)(ws + 78 * MB);     // over x1b (dead)
  u16*   hbb   = (u16*)(ws + 38 * MB);     // [38,70) over x1/cab/ca0 (all dead after ln3#2/cWo)
  float* yb0   = (float*)(ws + 2 * MB);    // [2,18) over kpk/vpk (dead after cross_attn)
  float* yb1   = (float*)(ws + 86 * MB);   // [86,102) over ca1 (dead after ln3#2)

  const int MROWS = BATCH * SEQ;  // 4096

  // ---- prep ----
  prep_misc<<<8528, 256, 0, stream>>>(x, xh, xl, mem, memb, idx,
                                      sbq, sbk, biasqk, cbk, cbv, cbkv);
  {
    PrepW p;
    p.s2[0] = sWq; p.dh2[0] = WqkhT;               p.dl2[0] = WqklT;
    p.s2[1] = sWk; p.dh2[1] = WqkhT + 1024 * 1024; p.dl2[1] = WqklT + 1024 * 1024;
    p.s6[0] = sWv; p.d6[0] = sWvT;
    p.s6[1] = sWo; p.d6[1] = sWoT;
    p.s6[2] = cWq; p.d6[2] = cWqT;
    p.s6[3] = cWk; p.d6[3] = cWkvT;
    p.s6[4] = cWv; p.d6[4] = cWkvT + 1024 * 1024;
    p.s6[5] = cWo; p.d6[5] = cWoT;
    p.W1 = W1; p.W1T = W1T; p.W2 = W2; p.W2T = W2T;
    prep_weights<<<4096, 256, 0, stream>>>(p);
  }

  // ---- self attention (ProbSparse) ----
  gemm4(xh, xl, WqkhT, WqklT, biasqk, qk, MROWS, 2048, DMODEL, stream);
  gemm(xh, sWvT, sbv, nullptr, vbf, MROWS, DMODEL, DMODEL, 0, stream);
  probM_kernel<<<BATCH * SEQ / 4, 256, 0, stream>>>(qk, idx, Mv);
  topk_kernel<<<BATCH * NHEADS, 256, 0, stream>>>(Mv, Mtop);
  kvpack_self<<<dim3(BATCH * NHEADS, SEQ / 64), 256, 0, stream>>>(qk, vbf, kpks, vpks);
  probAttn_kernel<<<dim3(BATCH * NHEADS, 8), 256, 0, stream>>>(qk, kpks, vpks, Mtop, Opart, mlbuf);
  scanA_kernel<<<dim3(BATCH * NHEADS, 16), 64, 0, stream>>>(vbf, csum);
  scanB_kernel<<<dim3(BATCH * NHEADS, 16), 64, 0, stream>>>(vbf, csum, ctxb);
  probCombine_kernel<<<BATCH * NHEADS * NTOP, 64, 0, stream>>>(Opart, mlbuf, Mtop, ctxb);
  gemmks(ctxb, sWoT, sbo, sa0, sa1, MROWS, DMODEL, DMODEL, stream);
  ln3_kernel<<<MROWS, 256, 0, stream>>>(x, sa0, sa1, g1, be1, x1, x1b);

  // ---- cross attention ----
  gemmks(x1b, cWqT, cbq, q20, q21, MROWS, DMODEL, DMODEL, stream);
  gemm(memb, cWkvT, cbkv, nullptr, kv2b, MROWS, 2048, DMODEL, 0, stream, 1);
  kvpack_kernel<<<dim3(BATCH * NHEADS, SEQ / 64), 256, 0, stream>>>(kv2b, kpk, vpk);
  cross_attn_kernel<<<dim3(BATCH * NHEADS, SEQ / 128, 2), 512, 0, stream>>>(q20, q21, kpk, vpk, Opb, lsb);
  caCombine_kernel<<<4096, 256, 0, stream>>>(Opb, lsb, cab);
  gemmks(cab, cWoT, cbo, ca0, ca1, MROWS, DMODEL, DMODEL, stream);
  ln3_kernel<<<MROWS, 256, 0, stream>>>(x1, ca0, ca1, g2, be2, x2, x2b);

  // ---- FFN ----
  gemm(x2b, W1T, b1, nullptr, hbb, MROWS, DFF, DMODEL, 1, stream, 1);
  gemmks(hbb, W2T, b2, yb0, yb1, MROWS, DMODEL, DFF, stream);
  ln3_kernel<<<MROWS, 256, 0, stream>>>(x2, yb0, yb1, g3, be3, outp, nullptr);
}

// Round 17
// 525.983 us; speedup vs baseline: 1.0109x; 1.0109x over previous
//
#include <hip/hip_runtime.h>

static constexpr int BATCH  = 2;
static constexpr int SEQ    = 2048;
static constexpr int DMODEL = 1024;
static constexpr int NHEADS = 16;
static constexpr int EHEAD  = 64;
static constexpr int DFF    = 4096;
static constexpr int NTOP   = 40;

typedef unsigned short u16;
typedef __bf16 bf16x8_t __attribute__((ext_vector_type(8)));
typedef u16    u16x8_t  __attribute__((ext_vector_type(8)));
typedef u16    u16x4_t  __attribute__((ext_vector_type(4)));
typedef float  f32x4_t  __attribute__((ext_vector_type(4)));

static constexpr float QSCALE = 0.125f * 1.44269504088896f;  // 1/8 * log2(e)
static constexpr float FIXM   = 12.0f;  // fixed softmax shift (log2 domain)

static __device__ __forceinline__ u16 f2b(float f) {
  unsigned u = __builtin_bit_cast(unsigned, f);
  unsigned r = u + 0x7FFFu + ((u >> 16) & 1u);
  return (u16)(r >> 16);
}
static __device__ __forceinline__ u16 f2bf(float f) {
  __bf16 h = (__bf16)f;
  return __builtin_bit_cast(u16, h);
}
static __device__ __forceinline__ float b2f(u16 h) {
  unsigned u = ((unsigned)h) << 16;
  return __builtin_bit_cast(float, u);
}
static __device__ __forceinline__ f32x4_t mfma_bf16(u16x8_t a, u16x8_t b, f32x4_t c) {
  return __builtin_amdgcn_mfma_f32_16x16x32_bf16(
      __builtin_bit_cast(bf16x8_t, a), __builtin_bit_cast(bf16x8_t, b), c, 0, 0, 0);
}

#define GLD16(gsrc, ldst)                                                        \
  __builtin_amdgcn_global_load_lds(                                             \
      (const __attribute__((address_space(1))) void*)(gsrc),                    \
      (__attribute__((address_space(3))) void*)(ldst), 16, 0, 0)

// ---------------------------------------------------------------- threefry
static __device__ __forceinline__ void tf2x32(unsigned k0, unsigned k1,
                                              unsigned x0, unsigned x1,
                                              unsigned& o0, unsigned& o1) {
  unsigned ks2 = 0x1BD11BDAu ^ k0 ^ k1;
  x0 += k0; x1 += k1;
#define TFR(r) { x0 += x1; x1 = (x1 << r) | (x1 >> (32 - r)); x1 ^= x0; }
  TFR(13) TFR(15) TFR(26) TFR(6)  x0 += k1;  x1 += ks2 + 1u;
  TFR(17) TFR(29) TFR(16) TFR(24) x0 += ks2; x1 += k0 + 2u;
  TFR(13) TFR(15) TFR(26) TFR(6)  x0 += k0;  x1 += k1 + 3u;
  TFR(17) TFR(29) TFR(16) TFR(24) x0 += k1;  x1 += ks2 + 4u;
  TFR(13) TFR(15) TFR(26) TFR(6)  x0 += ks2; x1 += k0 + 5u;
#undef TFR
  o0 = x0; o1 = x1;
}

// ---------------------------------------------------------------- prep (merged)
__global__ __launch_bounds__(256)
void prep_misc(const float* __restrict__ x, u16* __restrict__ xh,
               u16* __restrict__ xl, const float* __restrict__ mem,
               u16* __restrict__ memb, int* __restrict__ idx,
               const float* __restrict__ sbq, const float* __restrict__ sbk,
               float* __restrict__ biasqk, const float* __restrict__ cbk,
               const float* __restrict__ cbv, float* __restrict__ cbkv) {
  int blk = blockIdx.x, tid = threadIdx.x;
  if (blk < 4096) {
    int i = blk * 256 + tid;
    f32x4_t v = *(const f32x4_t*)(x + (size_t)i * 4);
    u16x4_t h, l;
#pragma unroll
    for (int d = 0; d < 4; ++d) {
      u16 hh = f2b(v[d]); h[d] = hh; l[d] = f2b(v[d] - b2f(hh));
    }
    *(u16x4_t*)(xh + (size_t)i * 4) = h;
    *(u16x4_t*)(xl + (size_t)i * 4) = l;
  } else if (blk < 8192) {
    int i = (blk - 4096) * 256 + tid;
    f32x4_t v = *(const f32x4_t*)(mem + (size_t)i * 4);
    u16x4_t o;
    o[0] = f2b(v[0]); o[1] = f2b(v[1]); o[2] = f2b(v[2]); o[3] = f2b(v[3]);
    *(u16x4_t*)(memb + (size_t)i * 4) = o;
  } else if (blk < 8512) {
    int i = (blk - 8192) * 256 + tid;          // 0..81919
    unsigned c0, c1, o0, o1;
    tf2x32(0u, 42u, 0u, 1u, c0, c1);           // k2 = second split child
    tf2x32(c0, c1, 0u, (unsigned)i, o0, o1);
    idx[i] = (int)((o0 ^ o1) & 2047u);
  } else {
    int i = (blk - 8512) * 256 + tid;          // 0..4095
    if (i < 1024) biasqk[i] = sbq[i];
    else if (i < 2048) biasqk[i] = sbk[i - 1024];
    else if (i < 3072) cbkv[i - 2048] = cbk[i - 2048];
    else cbkv[i - 2048] = cbv[i - 3072];
  }
}

struct PrepW {
  const float* s2[2]; u16* dh2[2]; u16* dl2[2];
  const float* s6[6]; u16* d6[6];
  const float* W1; u16* W1T; const float* W2; u16* W2T;
};
__global__ __launch_bounds__(256)
void prep_weights(PrepW p) {
  __shared__ float t[64][65];
  int j = blockIdx.x;
  int c = threadIdx.x & 63, r4 = threadIdx.x >> 6;
  const float* in; u16* oh; u16* ol = nullptr;
  int K, N, k0, n0;
  if (j < 512) {
    int m = j >> 8, jj = j & 255;
    in = p.s2[m]; oh = p.dh2[m]; ol = p.dl2[m];
    K = 1024; N = 1024; n0 = (jj & 15) * 64; k0 = (jj >> 4) * 64;
  } else if (j < 2048) {
    int m = (j - 512) >> 8, jj = (j - 512) & 255;
    in = p.s6[m]; oh = p.d6[m];
    K = 1024; N = 1024; n0 = (jj & 15) * 64; k0 = (jj >> 4) * 64;
  } else if (j < 3072) {
    int jj = j - 2048;
    in = p.W1; oh = p.W1T;
    K = 1024; N = 4096; n0 = (jj & 63) * 64; k0 = (jj >> 6) * 64;
  } else {
    int jj = j - 3072;
    in = p.W2; oh = p.W2T;
    K = 4096; N = 1024; n0 = (jj & 15) * 64; k0 = (jj >> 4) * 64;
  }
#pragma unroll
  for (int i = 0; i < 16; ++i) {
    int r = r4 * 16 + i;
    t[r][c] = in[(size_t)(k0 + r) * N + n0 + c];
  }
  __syncthreads();
#pragma unroll
  for (int i = 0; i < 16; ++i) {
    int r = r4 * 16 + i;
    float f = t[c][r];
    u16 h = f2b(f);
    oh[(size_t)(n0 + r) * K + k0 + c] = h;
    if (ol) ol[(size_t)(n0 + r) * K + k0 + c] = f2b(f - b2f(h));
  }
}

// ---------------------------------------------------------------- bf16 GEMM
template<int NF>
__global__ __launch_bounds__(256)
void gemm_bf(const u16* __restrict__ A, const u16* __restrict__ Bt,
             const float* __restrict__ bias, float* __restrict__ Cf,
             u16* __restrict__ Cb, int M, int N, int K, int relu) {
  __shared__ __align__(16) u16 sA[2][128 * 32];
  __shared__ __align__(16) u16 sB[2][NF * 32 * 32];
  const int tid = threadIdx.x;
  const int wave = tid >> 6, lane = tid & 63;
  const int m0 = blockIdx.x * 128, n0 = blockIdx.y * (NF * 32);
  const int wr = (wave >> 1) * 64, wc = (wave & 1) * (NF * 16);
  const int lr = lane & 15, kg = lane >> 4;
  const int wv = __builtin_amdgcn_readfirstlane(wave);

  int rowA[2], c8A[2];
#pragma unroll
  for (int rep = 0; rep < 2; ++rep) {
    int P = (rep * 256 + tid) << 4;
    int L = P ^ (((P >> 7) & 3) << 4);
    rowA[rep] = L >> 6; c8A[rep] = (L >> 4) & 3;
  }
  int rowB[NF / 2], c8B[NF / 2];
#pragma unroll
  for (int rep = 0; rep < NF / 2; ++rep) {
    int P = (rep * 256 + tid) << 4;
    int L = P ^ (((P >> 7) & 3) << 4);
    rowB[rep] = L >> 6; c8B[rep] = (L >> 4) & 3;
  }

  f32x4_t acc[4][NF];
#pragma unroll
  for (int i = 0; i < 4; ++i)
#pragma unroll
    for (int j = 0; j < NF; ++j) acc[i][j] = f32x4_t{0.f, 0.f, 0.f, 0.f};

  auto STAGE = [&](int buf, int k0) {
#pragma unroll
    for (int rep = 0; rep < 2; ++rep)
      GLD16(A + (size_t)(m0 + rowA[rep]) * K + k0 + c8A[rep] * 8,
            &sA[buf][(rep * 256 + wv * 64) * 8]);
#pragma unroll
    for (int rep = 0; rep < NF / 2; ++rep)
      GLD16(Bt + (size_t)(n0 + rowB[rep]) * K + k0 + c8B[rep] * 8,
            &sB[buf][(rep * 256 + wv * 64) * 8]);
  };

  const int nk = K >> 5;
  STAGE(0, 0);
  __syncthreads();
  for (int t = 0; t < nk; ++t) {
    const int cur = t & 1;
    if (t + 1 < nk) STAGE(cur ^ 1, (t + 1) << 5);
    u16x8_t a8[4], b8[NF];
#pragma unroll
    for (int mi = 0; mi < 4; ++mi) {
      int La = (wr + mi * 16 + lr) * 64 + kg * 16;
      a8[mi] = *(const u16x8_t*)((const char*)sA[cur] + (La ^ (((La >> 7) & 3) << 4)));
    }
#pragma unroll
    for (int ni = 0; ni < NF; ++ni) {
      int Lb = (wc + ni * 16 + lr) * 64 + kg * 16;
      b8[ni] = *(const u16x8_t*)((const char*)sB[cur] + (Lb ^ (((Lb >> 7) & 3) << 4)));
    }
#pragma unroll
    for (int mi = 0; mi < 4; ++mi)
#pragma unroll
      for (int ni = 0; ni < NF; ++ni)
        acc[mi][ni] = mfma_bf16(a8[mi], b8[ni], acc[mi][ni]);
    __syncthreads();
  }
#pragma unroll
  for (int ni = 0; ni < NF; ++ni) {
    int col = n0 + wc + ni * 16 + lr;
    float bc = bias[col];
#pragma unroll
    for (int mi = 0; mi < 4; ++mi)
#pragma unroll
      for (int r = 0; r < 4; ++r) {
        int row = m0 + wr + mi * 16 + kg * 4 + r;
        float vv = acc[mi][ni][r] + bc;
        if (relu) vv = fmaxf(vv, 0.f);
        if (Cf) Cf[(size_t)row * N + col] = vv;
        if (Cb) Cb[(size_t)row * N + col] = f2b(vv);
      }
  }
}

// K-split GEMM: blockIdx.z picks K-half; z=0 adds bias, writes C0; z=1 writes C1.
template<int NF>
__global__ __launch_bounds__(256)
void gemm_ks(const u16* __restrict__ A, const u16* __restrict__ Bt,
             const float* __restrict__ bias, float* __restrict__ C0,
             float* __restrict__ C1, int M, int N, int K) {
  __shared__ __align__(16) u16 sA[2][128 * 32];
  __shared__ __align__(16) u16 sB[2][NF * 32 * 32];
  const int tid = threadIdx.x;
  const int wave = tid >> 6, lane = tid & 63;
  const int m0 = blockIdx.x * 128, n0 = blockIdx.y * (NF * 32);
  const int zz = blockIdx.z;
  const int Kh = K >> 1;
  const u16* Ab = A + (size_t)zz * Kh;
  const u16* Bb = Bt + (size_t)zz * Kh;
  float* Cf = zz ? C1 : C0;
  const int wr = (wave >> 1) * 64, wc = (wave & 1) * (NF * 16);
  const int lr = lane & 15, kg = lane >> 4;
  const int wv = __builtin_amdgcn_readfirstlane(wave);

  int rowA[2], c8A[2];
#pragma unroll
  for (int rep = 0; rep < 2; ++rep) {
    int P = (rep * 256 + tid) << 4;
    int L = P ^ (((P >> 7) & 3) << 4);
    rowA[rep] = L >> 6; c8A[rep] = (L >> 4) & 3;
  }
  int rowB[NF / 2], c8B[NF / 2];
#pragma unroll
  for (int rep = 0; rep < NF / 2; ++rep) {
    int P = (rep * 256 + tid) << 4;
    int L = P ^ (((P >> 7) & 3) << 4);
    rowB[rep] = L >> 6; c8B[rep] = (L >> 4) & 3;
  }

  f32x4_t acc[4][NF];
#pragma unroll
  for (int i = 0; i < 4; ++i)
#pragma unroll
    for (int j = 0; j < NF; ++j) acc[i][j] = f32x4_t{0.f, 0.f, 0.f, 0.f};

  auto STAGE = [&](int buf, int k0) {
#pragma unroll
    for (int rep = 0; rep < 2; ++rep)
      GLD16(Ab + (size_t)(m0 + rowA[rep]) * K + k0 + c8A[rep] * 8,
            &sA[buf][(rep * 256 + wv * 64) * 8]);
#pragma unroll
    for (int rep = 0; rep < NF / 2; ++rep)
      GLD16(Bb + (size_t)(n0 + rowB[rep]) * K + k0 + c8B[rep] * 8,
            &sB[buf][(rep * 256 + wv * 64) * 8]);
  };

  const int nk = Kh >> 5;
  STAGE(0, 0);
  __syncthreads();
  for (int t = 0; t < nk; ++t) {
    const int cur = t & 1;
    if (t + 1 < nk) STAGE(cur ^ 1, (t + 1) << 5);
    u16x8_t a8[4], b8[NF];
#pragma unroll
    for (int mi = 0; mi < 4; ++mi) {
      int La = (wr + mi * 16 + lr) * 64 + kg * 16;
      a8[mi] = *(const u16x8_t*)((const char*)sA[cur] + (La ^ (((La >> 7) & 3) << 4)));
    }
#pragma unroll
    for (int ni = 0; ni < NF; ++ni) {
      int Lb = (wc + ni * 16 + lr) * 64 + kg * 16;
      b8[ni] = *(const u16x8_t*)((const char*)sB[cur] + (Lb ^ (((Lb >> 7) & 3) << 4)));
    }
#pragma unroll
    for (int mi = 0; mi < 4; ++mi)
#pragma unroll
      for (int ni = 0; ni < NF; ++ni)
        acc[mi][ni] = mfma_bf16(a8[mi], b8[ni], acc[mi][ni]);
    __syncthreads();
  }
#pragma unroll
  for (int ni = 0; ni < NF; ++ni) {
    int col = n0 + wc + ni * 16 + lr;
    float bc = (zz == 0) ? bias[col] : 0.f;
#pragma unroll
    for (int mi = 0; mi < 4; ++mi)
#pragma unroll
      for (int r = 0; r < 4; ++r) {
        int row = m0 + wr + mi * 16 + kg * 4 + r;
        Cf[(size_t)row * N + col] = acc[mi][ni][r] + bc;
      }
  }
}

// 3-term split GEMM (f32-equivalent: hi*hi + hi*lo + lo*hi)
template<int NF>
__global__ __launch_bounds__(256)
void gemm4_bf(const u16* __restrict__ Ah, const u16* __restrict__ Al,
              const u16* __restrict__ Bh, const u16* __restrict__ Bl,
              const float* __restrict__ bias, float* __restrict__ Cf,
              int M, int N, int K) {
  __shared__ __align__(16) u16 sAh[2][128 * 32];
  __shared__ __align__(16) u16 sAl[2][128 * 32];
  __shared__ __align__(16) u16 sBh[2][NF * 32 * 32];
  __shared__ __align__(16) u16 sBl[2][NF * 32 * 32];
  const int tid = threadIdx.x;
  const int wave = tid >> 6, lane = tid & 63;
  const int m0 = blockIdx.x * 128, n0 = blockIdx.y * (NF * 32);
  const int wr = (wave >> 1) * 64, wc = (wave & 1) * (NF * 16);
  const int lr = lane & 15, kg = lane >> 4;
  const int wv = __builtin_amdgcn_readfirstlane(wave);

  int rowA[2], c8A[2];
#pragma unroll
  for (int rep = 0; rep < 2; ++rep) {
    int P = (rep * 256 + tid) << 4;
    int L = P ^ (((P >> 7) & 3) << 4);
    rowA[rep] = L >> 6; c8A[rep] = (L >> 4) & 3;
  }
  int rowB[NF / 2], c8B[NF / 2];
#pragma unroll
  for (int rep = 0; rep < NF / 2; ++rep) {
    int P = (rep * 256 + tid) << 4;
    int L = P ^ (((P >> 7) & 3) << 4);
    rowB[rep] = L >> 6; c8B[rep] = (L >> 4) & 3;
  }

  f32x4_t acc[4][NF];
#pragma unroll
  for (int i = 0; i < 4; ++i)
#pragma unroll
    for (int j = 0; j < NF; ++j) acc[i][j] = f32x4_t{0.f, 0.f, 0.f, 0.f};

  auto STAGE = [&](int buf, int k0) {
#pragma unroll
    for (int rep = 0; rep < 2; ++rep) {
      GLD16(Ah + (size_t)(m0 + rowA[rep]) * K + k0 + c8A[rep] * 8,
            &sAh[buf][(rep * 256 + wv * 64) * 8]);
      GLD16(Al + (size_t)(m0 + rowA[rep]) * K + k0 + c8A[rep] * 8,
            &sAl[buf][(rep * 256 + wv * 64) * 8]);
    }
#pragma unroll
    for (int rep = 0; rep < NF / 2; ++rep) {
      GLD16(Bh + (size_t)(n0 + rowB[rep]) * K + k0 + c8B[rep] * 8,
            &sBh[buf][(rep * 256 + wv * 64) * 8]);
      GLD16(Bl + (size_t)(n0 + rowB[rep]) * K + k0 + c8B[rep] * 8,
            &sBl[buf][(rep * 256 + wv * 64) * 8]);
    }
  };

  const int nk = K >> 5;
  STAGE(0, 0);
  __syncthreads();
  for (int t = 0; t < nk; ++t) {
    const int cur = t & 1;
    if (t + 1 < nk) STAGE(cur ^ 1, (t + 1) << 5);
    u16x8_t ah[4], al[4], bh[NF], bl[NF];
#pragma unroll
    for (int mi = 0; mi < 4; ++mi) {
      int La = (wr + mi * 16 + lr) * 64 + kg * 16;
      int off = La ^ (((La >> 7) & 3) << 4);
      ah[mi] = *(const u16x8_t*)((const char*)sAh[cur] + off);
      al[mi] = *(const u16x8_t*)((const char*)sAl[cur] + off);
    }
#pragma unroll
    for (int ni = 0; ni < NF; ++ni) {
      int Lb = (wc + ni * 16 + lr) * 64 + kg * 16;
      int off = Lb ^ (((Lb >> 7) & 3) << 4);
      bh[ni] = *(const u16x8_t*)((const char*)sBh[cur] + off);
      bl[ni] = *(const u16x8_t*)((const char*)sBl[cur] + off);
    }
#pragma unroll
    for (int mi = 0; mi < 4; ++mi)
#pragma unroll
      for (int ni = 0; ni < NF; ++ni) {
        acc[mi][ni] = mfma_bf16(ah[mi], bh[ni], acc[mi][ni]);
        acc[mi][ni] = mfma_bf16(ah[mi], bl[ni], acc[mi][ni]);
        acc[mi][ni] = mfma_bf16(al[mi], bh[ni], acc[mi][ni]);
      }
    __syncthreads();
  }
#pragma unroll
  for (int ni = 0; ni < NF; ++ni) {
    int col = n0 + wc + ni * 16 + lr;
    float bc = bias[col];
#pragma unroll
    for (int mi = 0; mi < 4; ++mi)
#pragma unroll
      for (int r = 0; r < 4; ++r) {
        int row = m0 + wr + mi * 16 + kg * 4 + r;
        Cf[(size_t)row * N + col] = acc[mi][ni][r] + bc;
      }
  }
}

// ---------------------------------------------------------------- ProbSparse
__global__ __launch_bounds__(256)
void probM_kernel(const float* __restrict__ qk, const int* __restrict__ idx,
                  float* __restrict__ Mv) {
  int blk = blockIdx.x;                        // 0..1023
  int xcd = blk & 7, j = blk >> 3;             // j: 0..127
  int b = xcd >> 2;
  int part = (xcd & 3) * 128 + j;              // 0..511
  int l = part * 4 + (threadIdx.x >> 6);
  int lane = threadIdx.x & 63;
  const float* qrow = qk + ((size_t)b * SEQ + l) * 2048 + lane * 16;
  f32x4_t qv0 = *(const f32x4_t*)(qrow);
  f32x4_t qv1 = *(const f32x4_t*)(qrow + 4);
  f32x4_t qv2 = *(const f32x4_t*)(qrow + 8);
  f32x4_t qv3 = *(const f32x4_t*)(qrow + 12);
  const int* ip = idx + l * NTOP;
  const float* kbase = qk + (size_t)b * SEQ * 2048 + 1024 + lane * 16;
  float mmax = -3.0e38f, msum = 0.f;
  for (int pass = 0; pass < 4; ++pass) {
    int lo = pass << 9;
#pragma unroll 4
    for (int u = 0; u < NTOP; ++u) {
      int ki = ip[u];
      if ((unsigned)(ki - lo) < 512u) {        // wave-uniform branch
        const float* kr = kbase + (size_t)ki * 2048;
        f32x4_t k0 = *(const f32x4_t*)(kr);
        f32x4_t k1 = *(const f32x4_t*)(kr + 4);
        f32x4_t k2 = *(const f32x4_t*)(kr + 8);
        f32x4_t k3 = *(const f32x4_t*)(kr + 12);
        float p = qv0[0] * k0[0] + qv0[1] * k0[1] + qv0[2] * k0[2] + qv0[3] * k0[3]
                + qv1[0] * k1[0] + qv1[1] * k1[1] + qv1[2] * k1[2] + qv1[3] * k1[3]
                + qv2[0] * k2[0] + qv2[1] * k2[1] + qv2[2] * k2[2] + qv2[3] * k2[3]
                + qv3[0] * k3[0] + qv3[1] * k3[1] + qv3[2] * k3[2] + qv3[3] * k3[3];
        p += __shfl_xor(p, 1);
        p += __shfl_xor(p, 2);
        mmax = fmaxf(mmax, p);
        msum += p;
      }
    }
  }
  if ((lane & 3) == 0) {
    int hh = lane >> 2;
    Mv[((size_t)b * NHEADS + hh) * SEQ + l] = mmax - msum * (1.f / 2048.f);
  }
}

// register-resident iterative top-40
__global__ __launch_bounds__(256)
void topk_kernel(const float* __restrict__ Mv, int* __restrict__ Mtop) {
  int bh = blockIdx.x;
  int tid = threadIdx.x;
  int lane = tid & 63, wv = tid >> 6;
  float v8[8];
#pragma unroll
  for (int j = 0; j < 8; ++j) v8[j] = Mv[bh * 2048 + j * 256 + tid];
  __shared__ float wrv[4];
  __shared__ int wri[4];
  __shared__ int winner;
  for (int it = 0; it < NTOP; ++it) {
    float best = v8[0];
    int bj = 0;
#pragma unroll
    for (int j = 1; j < 8; ++j)
      if (v8[j] > best) { best = v8[j]; bj = j; }
    int bi = bj * 256 + tid;
#pragma unroll
    for (int m = 1; m < 64; m <<= 1) {
      float ov = __shfl_xor(best, m);
      int oi = __shfl_xor(bi, m);
      if (ov > best || (ov == best && oi < bi)) { best = ov; bi = oi; }
    }
    if (lane == 0) { wrv[wv] = best; wri[wv] = bi; }
    __syncthreads();
    if (tid == 0) {
      float bv = wrv[0]; int bbi = wri[0];
#pragma unroll
      for (int t = 1; t < 4; ++t)
        if (wrv[t] > bv || (wrv[t] == bv && wri[t] < bbi)) { bv = wrv[t]; bbi = wri[t]; }
      Mtop[bh * NTOP + it] = bbi;
      winner = bbi;
    }
    __syncthreads();
    int w = winner;
#pragma unroll
    for (int j = 0; j < 8; ++j)
      if ((w >> 8) == j && (w & 255) == tid) v8[j] = -3.4e38f;
  }
}

// ---------------------------------------------------------------- kv pack (self)
__global__ __launch_bounds__(256)
void kvpack_self(const float* __restrict__ qk, const u16* __restrict__ vbf,
                 u16* __restrict__ kpack, u16* __restrict__ vpack) {
  int bh = blockIdx.x, ch = blockIdx.y;
  int b = bh >> 4, hh = bh & 15;
  int tid = threadIdx.x;
  __shared__ u16 vt[64][80];
#pragma unroll
  for (int rep = 0; rep < 2; ++rep) {
    int u = rep * 256 + tid;
    int key = u >> 3, c = u & 7;
    const float* ksrc = qk + ((size_t)(b * SEQ + ch * 64 + key)) * 2048 + 1024 + hh * 64 + c * 8;
    f32x4_t k0 = *(const f32x4_t*)ksrc;
    f32x4_t k1 = *(const f32x4_t*)(ksrc + 4);
    u16x8_t d;
    d[0] = f2bf(k0[0]); d[1] = f2bf(k0[1]); d[2] = f2bf(k0[2]); d[3] = f2bf(k0[3]);
    d[4] = f2bf(k1[0]); d[5] = f2bf(k1[1]); d[6] = f2bf(k1[2]); d[7] = f2bf(k1[3]);
    int slot = (key & 3) | (((key >> 3) & 1) << 2);
    *(u16x8_t*)(kpack + ((size_t)bh * SEQ + ch * 64 + key) * 64 + ((c ^ slot) * 8)) = d;
    u16x8_t dv = *(const u16x8_t*)(vbf + ((size_t)(b * SEQ + ch * 64 + key)) * 1024 + hh * 64 + c * 8);
    *(u16x8_t*)(&vt[key][c * 8]) = dv;
  }
  __syncthreads();
#pragma unroll
  for (int rep = 0; rep < 2; ++rep) {
    int u = rep * 256 + tid;
    int e = u >> 3, c = u & 7;
    int kb = (c ^ (e & 7)) * 8;
    u16x8_t d;
#pragma unroll
    for (int j = 0; j < 8; ++j) d[j] = vt[kb + j][e];
    *(u16x8_t*)(vpack + (((size_t)bh * 32 + ch) * 64 + e) * 64 + c * 8) = d;
  }
}

// ---------------------------------------------------------------- probAttn
__global__ __launch_bounds__(256)
void probAttn_kernel(const float* __restrict__ qk, const u16* __restrict__ kpack,
                     const u16* __restrict__ vpack, const int* __restrict__ Mtop,
                     float* __restrict__ Opart, float* __restrict__ ml) {
  const int bh = blockIdx.x, b = bh >> 4, hh = bh & 15;
  const int split = blockIdx.y;                 // 0..7 (256 keys each)
  const int tid = threadIdx.x, wave = tid >> 6, lane = tid & 63;
  const int lr = lane & 15, kg = lane >> 4;
  const int wv = __builtin_amdgcn_readfirstlane(wave);
  __shared__ __align__(16) u16 Qs[48 * 64];
  __shared__ __align__(16) u16 Kt[2][64 * 64];
  __shared__ __align__(16) u16 Vt[2][64 * 64];

#pragma unroll
  for (int rep = 0; rep < 3; ++rep) {
    int j = tid + 256 * rep;        // 0..767
    int row = j >> 4, c4 = j & 15;
    int qi = Mtop[bh * NTOP + (row < NTOP ? row : NTOP - 1)];
    f32x4_t v4 = *(const f32x4_t*)(qk + ((size_t)b * SEQ + qi) * 2048 + hh * EHEAD + c4 * 4);
    u16x4_t b4;
    b4[0] = f2bf(v4[0] * QSCALE); b4[1] = f2bf(v4[1] * QSCALE);
    b4[2] = f2bf(v4[2] * QSCALE); b4[3] = f2bf(v4[3] * QSCALE);
    *(u16x4_t*)((char*)Qs + ((row * 128 + c4 * 8) ^ ((row & 7) << 4))) = b4;
  }

  const int qtile = (wave < 3) ? wave : 2;
  const int qrow_g = qtile * 16 + lr;
  const int iq = (qrow_g < NTOP) ? Mtop[bh * NTOP + qrow_g] : -1;

  int koffs[2][4], voffs[2][4], kbase16[4];
#pragma unroll
  for (int t4 = 0; t4 < 4; ++t4) {
    int arow = ((t4 >> 1) << 5) + ((lr >> 2) << 3) + ((t4 & 1) << 2) + (lr & 3);
    int slot = (arow & 3) | (((arow >> 3) & 1) << 2);
#pragma unroll
    for (int ks = 0; ks < 2; ++ks)
      koffs[ks][t4] = ((arow << 7) + (ks << 6) + (kg << 4)) ^ (slot << 4);
    kbase16[t4] = ((t4 >> 1) << 5) + (kg << 3) + ((t4 & 1) << 2);
  }
#pragma unroll
  for (int ne = 0; ne < 4; ++ne) {
    int e = ne * 16 + lr;
#pragma unroll
    for (int ks2 = 0; ks2 < 2; ++ks2)
      voffs[ks2][ne] = ((e << 7) + (ks2 << 6) + (kg << 4)) ^ ((e & 7) << 4);
  }
  const int maskbase = split * 256 - iq;

  const char* kgl = (const char*)kpack + (size_t)bh * SEQ * 128 + (size_t)split * 4 * 8192;
  const char* vgl = (const char*)vpack + (size_t)bh * 32 * 8192 + (size_t)split * 4 * 8192;
  auto STAGE = [&](int buf, int t) {
    GLD16(kgl + (size_t)t * 8192 + wv * 2048 + lane * 16, (char*)Kt[buf] + wv * 2048);
    GLD16(kgl + (size_t)t * 8192 + wv * 2048 + 1024 + lane * 16, (char*)Kt[buf] + wv * 2048 + 1024);
    GLD16(vgl + (size_t)t * 8192 + wv * 2048 + lane * 16, (char*)Vt[buf] + wv * 2048);
    GLD16(vgl + (size_t)t * 8192 + wv * 2048 + 1024 + lane * 16, (char*)Vt[buf] + wv * 2048 + 1024);
  };

  STAGE(0, 0);
  __syncthreads();

  u16x8_t bq[2];
  {
    int qrow = qtile * 16 + lr;
#pragma unroll
    for (int ks = 0; ks < 2; ++ks)
      bq[ks] = *(u16x8_t*)((char*)Qs + ((qrow * 128 + ks * 64 + kg * 16) ^ ((qrow & 7) << 4)));
  }

  f32x4_t oacc[4];
#pragma unroll
  for (int i = 0; i < 4; ++i) oacc[i] = f32x4_t{0.f, 0.f, 0.f, 0.f};
  float lsum = 0.f;

  for (int t = 0; t < 4; ++t) {
    const int cur = t & 1;
    if (t + 1 < 4) STAGE(cur ^ 1, t + 1);
    const char* kb = (const char*)Kt + cur * 8192;
    const char* vb = (const char*)Vt + cur * 8192;
    f32x4_t s[4];
#pragma unroll
    for (int i = 0; i < 4; ++i) s[i] = f32x4_t{-FIXM, -FIXM, -FIXM, -FIXM};
#pragma unroll
    for (int ks = 0; ks < 2; ++ks)
#pragma unroll
      for (int t4 = 0; t4 < 4; ++t4) {
        u16x8_t ak = *(const u16x8_t*)(kb + koffs[ks][t4]);
        s[t4] = mfma_bf16(ak, bq[ks], s[t4]);
      }
    const int mb = t * 64 + maskbase;
#pragma unroll
    for (int t4 = 0; t4 < 4; ++t4)
#pragma unroll
      for (int r = 0; r < 4; ++r)
        if (mb + kbase16[t4] + r > 0) s[t4][r] = -1e9f;
#pragma unroll
    for (int t4 = 0; t4 < 4; ++t4)
#pragma unroll
      for (int r = 0; r < 4; ++r) {
        float p = exp2f(s[t4][r]);
        s[t4][r] = p; lsum += p;
      }
#pragma unroll
    for (int ks2 = 0; ks2 < 2; ++ks2) {
      u16x8_t pa;
#pragma unroll
      for (int j = 0; j < 4; ++j) {
        pa[j] = f2bf(s[2 * ks2][j]);
        pa[4 + j] = f2bf(s[2 * ks2 + 1][j]);
      }
#pragma unroll
      for (int ne = 0; ne < 4; ++ne) {
        u16x8_t bv = *(const u16x8_t*)(vb + voffs[ks2][ne]);
        oacc[ne] = mfma_bf16(pa, bv, oacc[ne]);
      }
    }
    __syncthreads();
  }

  lsum += __shfl_xor(lsum, 16);
  lsum += __shfl_xor(lsum, 32);

  if (wave < 3) {
    float* ob = Opart + (((size_t)(bh * 8 + split)) * 48 + qtile * 16) * 64;
#pragma unroll
    for (int ne = 0; ne < 4; ++ne)
#pragma unroll
      for (int r = 0; r < 4; ++r)
        ob[(size_t)(kg * 4 + r) * 64 + ne * 16 + lr] = oacc[ne][r];
    if (kg == 0)
      ml[((size_t)(bh * 8 + split)) * 48 + qtile * 16 + lr] = lsum;
  }
}

__global__ __launch_bounds__(64)
void probCombine_kernel(const float* __restrict__ Opart, const float* __restrict__ ml,
                        const int* __restrict__ Mtop, u16* __restrict__ ctxb) {
  int bh = blockIdx.x / NTOP, q = blockIdx.x % NTOP;
  int e = threadIdx.x;
  int b = bh >> 4, hh = bh & 15;
  float lstar = 0.f, acc = 0.f;
#pragma unroll
  for (int s = 0; s < 8; ++s) {
    lstar += ml[((size_t)(bh * 8 + s)) * 48 + q];
    acc += Opart[(((size_t)(bh * 8 + s)) * 48 + q) * 64 + e];
  }
  int row = Mtop[bh * NTOP + q];
  ctxb[((size_t)b * SEQ + row) * DMODEL + hh * EHEAD + e] = f2bf(acc / lstar);
}

// ---------------------------------------------------------------- scans
__global__ __launch_bounds__(64)
void scanA_kernel(const u16* __restrict__ v, float* __restrict__ csum) {
  int bh = blockIdx.x, ch = blockIdx.y;
  int b = bh >> 4, hh = bh & 15, e = threadIdx.x;
  size_t base = ((size_t)b * SEQ + ch * 128) * DMODEL + hh * EHEAD + e;
  float run = 0.f;
  for (int i = 0; i < 128; ++i) run += b2f(v[base + (size_t)i * DMODEL]);
  csum[(bh * 16 + ch) * 64 + e] = run;
}
__global__ __launch_bounds__(64)
void scanB_kernel(const u16* __restrict__ v, const float* __restrict__ csum,
                  u16* __restrict__ ctxb) {
  int bh = blockIdx.x, ch = blockIdx.y;
  int b = bh >> 4, hh = bh & 15, e = threadIdx.x;
  float run = 0.f;
  for (int cc = 0; cc < ch; ++cc) run += csum[(bh * 16 + cc) * 64 + e];
  size_t base = ((size_t)b * SEQ + ch * 128) * DMODEL + hh * EHEAD + e;
  for (int i = 0; i < 128; ++i) {
    run += b2f(v[base + (size_t)i * DMODEL]);
    ctxb[base + (size_t)i * DMODEL] = f2bf(run);
  }
}

// ---------------------------------------------------------------- kv pack (cross)
__global__ __launch_bounds__(256)
void kvpack_kernel(const u16* __restrict__ kv, u16* __restrict__ kpack,
                   u16* __restrict__ vpack) {
  int bh = blockIdx.x, ch = blockIdx.y;
  int b = bh >> 4, hh = bh & 15;
  int tid = threadIdx.x;
  __shared__ u16 vt[64][80];
#pragma unroll
  for (int rep = 0; rep < 2; ++rep) {
    int u = rep * 256 + tid;
    int key = u >> 3, c = u & 7;
    u16x8_t d = *(const u16x8_t*)(kv + ((size_t)(b * SEQ + ch * 64 + key)) * 2048 + hh * 64 + c * 8);
    int slot = (key & 3) | (((key >> 3) & 1) << 2);
    *(u16x8_t*)(kpack + ((size_t)bh * SEQ + ch * 64 + key) * 64 + ((c ^ slot) * 8)) = d;
    u16x8_t dv = *(const u16x8_t*)(kv + ((size_t)(b * SEQ + ch * 64 + key)) * 2048 + 1024 + hh * 64 + c * 8);
    *(u16x8_t*)(&vt[key][c * 8]) = dv;
  }
  __syncthreads();
#pragma unroll
  for (int rep = 0; rep < 2; ++rep) {
    int u = rep * 256 + tid;
    int e = u >> 3, c = u & 7;
    int kb = (c ^ (e & 7)) * 8;
    u16x8_t d;
#pragma unroll
    for (int j = 0; j < 8; ++j) d[j] = vt[kb + j][e];
    *(u16x8_t*)(vpack + (((size_t)bh * 32 + ch) * 64 + e) * 64 + c * 8) = d;
  }
}

// ---------------------------------------------------------------- cross attn
__global__ __launch_bounds__(512)
void cross_attn_kernel(const float* __restrict__ q2, const u16* __restrict__ kpack,
                       const u16* __restrict__ vpack, u16* __restrict__ cab) {
  const int bh = blockIdx.x, b = bh >> 4, hh = bh & 15;
  const int qt0 = blockIdx.y * 128;
  const int tid = threadIdx.x, wave = tid >> 6, lane = tid & 63;
  const int lr = lane & 15, kg = lane >> 4;
  const int wv = __builtin_amdgcn_readfirstlane(wave);
  __shared__ __align__(16) u16 Qs[128 * 64];
  __shared__ __align__(16) u16 Kt[2][64 * 64];
  __shared__ __align__(16) u16 Vt[2][64 * 64];

#pragma unroll
  for (int i = 0; i < 4; ++i) {
    int j = tid + 512 * i;
    int row = j >> 4, c4 = j & 15;
    f32x4_t v4 = *(const f32x4_t*)(q2 + ((size_t)b * SEQ + qt0 + row) * DMODEL + hh * EHEAD + c4 * 4);
    u16x4_t b4;
    b4[0] = f2bf(v4[0] * QSCALE); b4[1] = f2bf(v4[1] * QSCALE);
    b4[2] = f2bf(v4[2] * QSCALE); b4[3] = f2bf(v4[3] * QSCALE);
    *(u16x4_t*)((char*)Qs + ((row * 128 + c4 * 8) ^ ((row & 7) << 4))) = b4;
  }

  int koffs[2][4], voffs[2][4];
#pragma unroll
  for (int t4 = 0; t4 < 4; ++t4) {
    int arow = ((t4 >> 1) << 5) + ((lr >> 2) << 3) + ((t4 & 1) << 2) + (lr & 3);
    int slot = (arow & 3) | (((arow >> 3) & 1) << 2);
#pragma unroll
    for (int ks = 0; ks < 2; ++ks)
      koffs[ks][t4] = ((arow << 7) + (ks << 6) + (kg << 4)) ^ (slot << 4);
  }
#pragma unroll
  for (int ne = 0; ne < 4; ++ne) {
    int e = ne * 16 + lr;
#pragma unroll
    for (int ks2 = 0; ks2 < 2; ++ks2)
      voffs[ks2][ne] = ((e << 7) + (ks2 << 6) + (kg << 4)) ^ ((e & 7) << 4);
  }

  const char* kgl = (const char*)kpack + (size_t)bh * SEQ * 128;
  const char* vgl = (const char*)vpack + (size_t)bh * 32 * 8192;
  auto STAGE = [&](int buf, int t) {
    GLD16(kgl + (size_t)t * 8192 + wv * 1024 + lane * 16, (char*)Kt[buf] + wv * 1024);
    GLD16(vgl + (size_t)t * 8192 + wv * 1024 + lane * 16, (char*)Vt[buf] + wv * 1024);
  };

  STAGE(0, 0);
  __syncthreads();

  u16x8_t bq[2];
  {
    int qrow = wave * 16 + lr;
#pragma unroll
    for (int ks = 0; ks < 2; ++ks)
      bq[ks] = *(u16x8_t*)((char*)Qs + ((qrow * 128 + ks * 64 + kg * 16) ^ ((qrow & 7) << 4)));
  }

  f32x4_t oacc[4];
#pragma unroll
  for (int i = 0; i < 4; ++i) oacc[i] = f32x4_t{0.f, 0.f, 0.f, 0.f};
  float lsum = 0.f;

  for (int t = 0; t < 32; ++t) {
    const int cur = t & 1;
    if (t + 1 < 32) STAGE(cur ^ 1, t + 1);
    const char* kb = (const char*)Kt + cur * 8192;
    const char* vb = (const char*)Vt + cur * 8192;
    f32x4_t s[4];
#pragma unroll
    for (int i = 0; i < 4; ++i) s[i] = f32x4_t{-FIXM, -FIXM, -FIXM, -FIXM};
#pragma unroll
    for (int ks = 0; ks < 2; ++ks)
#pragma unroll
      for (int t4 = 0; t4 < 4; ++t4) {
        u16x8_t ak = *(const u16x8_t*)(kb + koffs[ks][t4]);
        s[t4] = mfma_bf16(ak, bq[ks], s[t4]);
      }
#pragma unroll
    for (int t4 = 0; t4 < 4; ++t4)
#pragma unroll
      for (int r = 0; r < 4; ++r) {
        float p = exp2f(s[t4][r]);
        s[t4][r] = p; lsum += p;
      }
#pragma unroll
    for (int ks2 = 0; ks2 < 2; ++ks2) {
      u16x8_t pa;
#pragma unroll
      for (int j = 0; j < 4; ++j) {
        pa[j] = f2bf(s[2 * ks2][j]);
        pa[4 + j] = f2bf(s[2 * ks2 + 1][j]);
      }
#pragma unroll
      for (int ne = 0; ne < 4; ++ne) {
        u16x8_t bv = *(const u16x8_t*)(vb + voffs[ks2][ne]);
        oacc[ne] = mfma_bf16(pa, bv, oacc[ne]);
      }
    }
    __syncthreads();
  }

  lsum += __shfl_xor(lsum, 16);
  lsum += __shfl_xor(lsum, 32);
  float inv4[4];
#pragma unroll
  for (int r = 0; r < 4; ++r) inv4[r] = 1.0f / __shfl(lsum, kg * 4 + r);
#pragma unroll
  for (int ne = 0; ne < 4; ++ne)
#pragma unroll
    for (int r = 0; r < 4; ++r) {
      int row = qt0 + wave * 16 + kg * 4 + r;
      int col = hh * EHEAD + ne * 16 + lr;
      cab[((size_t)b * SEQ + row) * DMODEL + col] = f2bf(oacc[ne][r] * inv4[r]);
    }
}

// ---------------------------------------------------------------- layernorm
__global__ __launch_bounds__(256)
void ln_kernel(const float* __restrict__ x, const float* __restrict__ r,
               const float* __restrict__ g, const float* __restrict__ be,
               float* __restrict__ outf, u16* __restrict__ outb) {
  int row = blockIdx.x, tid = threadIdx.x;
  size_t base = (size_t)row * DMODEL;
  float v[4];
  float s = 0.f, sq = 0.f;
#pragma unroll
  for (int i = 0; i < 4; ++i) {
    int c = tid + i * 256;
    float t = x[base + c] + r[base + c];
    v[i] = t; s += t; sq += t * t;
  }
  __shared__ float rs[256], rq[256];
  rs[tid] = s; rq[tid] = sq;
  __syncthreads();
  for (int st = 128; st > 0; st >>= 1) {
    if (tid < st) { rs[tid] += rs[tid + st]; rq[tid] += rq[tid + st]; }
    __syncthreads();
  }
  float mean = rs[0] * (1.f / DMODEL);
  float var = rq[0] * (1.f / DMODEL) - mean * mean;
  float rstd = rsqrtf(var + 1e-5f);
#pragma unroll
  for (int i = 0; i < 4; ++i) {
    int c = tid + i * 256;
    float o = (v[i] - mean) * rstd * g[c] + be[c];
    if (outf) outf[base + c] = o;
    if (outb) outb[base + c] = f2bf(o);
  }
}

// 3-input layernorm: t = x + r0 + r1 (K-split GEMM partials)
__global__ __launch_bounds__(256)
void ln3_kernel(const float* __restrict__ x, const float* __restrict__ r0,
                const float* __restrict__ r1, const float* __restrict__ g,
                const float* __restrict__ be, float* __restrict__ outf,
                u16* __restrict__ outb) {
  int row = blockIdx.x, tid = threadIdx.x;
  size_t base = (size_t)row * DMODEL;
  float v[4];
  float s = 0.f, sq = 0.f;
#pragma unroll
  for (int i = 0; i < 4; ++i) {
    int c = tid + i * 256;
    float t = x[base + c] + r0[base + c] + r1[base + c];
    v[i] = t; s += t; sq += t * t;
  }
  __shared__ float rs[256], rq[256];
  rs[tid] = s; rq[tid] = sq;
  __syncthreads();
  for (int st = 128; st > 0; st >>= 1) {
    if (tid < st) { rs[tid] += rs[tid + st]; rq[tid] += rq[tid + st]; }
    __syncthreads();
  }
  float mean = rs[0] * (1.f / DMODEL);
  float var = rq[0] * (1.f / DMODEL) - mean * mean;
  float rstd = rsqrtf(var + 1e-5f);
#pragma unroll
  for (int i = 0; i < 4; ++i) {
    int c = tid + i * 256;
    float o = (v[i] - mean) * rstd * g[c] + be[c];
    if (outf) outf[base + c] = o;
    if (outb) outb[base + c] = f2bf(o);
  }
}

// ---------------------------------------------------------------- host side
static inline void gemm(const u16* A, const u16* Bt, const float* bias, float* Cf,
                        u16* Cb, int M, int N, int K, int relu, hipStream_t s,
                        int big = 0) {
  if (big)
    gemm_bf<4><<<dim3(M / 128, N / 128), 256, 0, s>>>(A, Bt, bias, Cf, Cb, M, N, K, relu);
  else
    gemm_bf<2><<<dim3(M / 128, N / 64), 256, 0, s>>>(A, Bt, bias, Cf, Cb, M, N, K, relu);
}
static inline void gemmks(const u16* A, const u16* Bt, const float* bias, float* C0,
                          float* C1, int M, int N, int K, hipStream_t s) {
  gemm_ks<4><<<dim3(M / 128, N / 128, 2), 256, 0, s>>>(A, Bt, bias, C0, C1, M, N, K);
}
static inline void gemm4(const u16* Ah, const u16* Al, const u16* Bh, const u16* Bl,
                         const float* bias, float* Cf, int M, int N, int K, hipStream_t s) {
  gemm4_bf<4><<<dim3(M / 128, N / 128), 256, 0, s>>>(Ah, Al, Bh, Bl, bias, Cf, M, N, K);
}

extern "C" void kernel_launch(void* const* d_in, const int* in_sizes, int n_in,
                              void* d_out, int out_size, void* d_ws, size_t ws_size,
                              hipStream_t stream) {
  const float* x   = (const float*)d_in[0];
  const float* mem = (const float*)d_in[1];
  const float* sWq = (const float*)d_in[2];  const float* sbq = (const float*)d_in[3];
  const float* sWk = (const float*)d_in[4];  const float* sbk = (const float*)d_in[5];
  const float* sWv = (const float*)d_in[6];  const float* sbv = (const float*)d_in[7];
  const float* sWo = (const float*)d_in[8];  const float* sbo = (const float*)d_in[9];
  const float* cWq = (const float*)d_in[10]; const float* cbq = (const float*)d_in[11];
  const float* cWk = (const float*)d_in[12]; const float* cbk = (const float*)d_in[13];
  const float* cWv = (const float*)d_in[14]; const float* cbv = (const float*)d_in[15];
  const float* cWo = (const float*)d_in[16]; const float* cbo = (const float*)d_in[17];
  const float* W1  = (const float*)d_in[18]; const float* b1  = (const float*)d_in[19];
  const float* W2  = (const float*)d_in[20]; const float* b2  = (const float*)d_in[21];
  const float* g1  = (const float*)d_in[22]; const float* be1 = (const float*)d_in[23];
  const float* g2  = (const float*)d_in[24]; const float* be2 = (const float*)d_in[25];
  const float* g3  = (const float*)d_in[26]; const float* be3 = (const float*)d_in[27];
  float* outp = (float*)d_out;
  char* ws = (char*)d_ws;
  const size_t MB = 1ull << 20;

  int*   idx    = (int*)(ws);
  float* Mv     = (float*)(ws + 0x60000);
  int*   Mtop   = (int*)(ws + 0xA0000);
  float* biasqk = (float*)(ws + 0x120000);
  float* cbkv   = (float*)(ws + 0x122000);
  float* csum   = (float*)(ws + 0x130000);   // 128KB

  u16* WqkhT = (u16*)(ws + 2 * MB);    // [2048][1024]
  u16* WqklT = (u16*)(ws + 6 * MB);
  u16* sWvT  = (u16*)(ws + 10 * MB);
  u16* sWoT  = (u16*)(ws + 12 * MB);
  u16* cWqT  = (u16*)(ws + 14 * MB);
  u16* cWkvT = (u16*)(ws + 16 * MB);   // [2048][1024]
  u16* cWoT  = (u16*)(ws + 20 * MB);
  u16* W1T   = (u16*)(ws + 22 * MB);
  u16* W2T   = (u16*)(ws + 30 * MB);

  u16* xh   = (u16*)(ws + 38 * MB);
  u16* xl   = (u16*)(ws + 46 * MB);
  u16* memb = (u16*)(ws + 54 * MB);

  float* qk    = (float*)(ws + 62 * MB);   // [4096][2048] f32, 32MB [62,94)
  u16*   vbf   = (u16*)(ws + 94 * MB);     // 8MB [94,102)
  u16*   kpks  = (u16*)(ws + 102 * MB);    // 8MB [102,110) self K packed
  u16*   vpks  = (u16*)(ws + 46 * MB);     // 8MB (over xl, dead after gemm4)
  float* Opart = (float*)(ws + 110 * MB);  // 3MB [110,113)
  float* mlbuf = (float*)(ws + 113 * MB);  // 49KB
  u16*   ctxb  = (u16*)(ws + 78 * MB);
  float* sa    = (float*)(ws + 94 * MB);   // reuse vbf+kpks
  float* x1    = (float*)(ws + 62 * MB);
  u16*   x1b   = (u16*)(ws + 78 * MB);
  float* q2    = (float*)(ws + 94 * MB);
  u16*   kv2b  = (u16*)(ws + 38 * MB);     // [4096][2048] bf16, 16MB [38,54)
  u16*   kpk   = (u16*)(ws + 54 * MB);     // 8MB (over memb, dead)
  u16*   vpk   = (u16*)(ws + 110 * MB);    // 8MB (over Opart, dead)
  u16*   cab   = (u16*)(ws + 38 * MB);
  float* ca0   = (float*)(ws + 94 * MB);   // over q2 (dead after cross_attn)
  float* ca1   = (float*)(ws + 2 * MB);    // over weight transposes (dead)
  float* x2    = (float*)(ws + 38 * MB);
  u16*   x2b   = (u16*)(ws + 54 * MB);
  u16*   hbb   = (u16*)(ws + 62 * MB);     // 32MB [62,94)
  float* yb0   = (float*)(ws + 94 * MB);
  float* yb1   = (float*)(ws + 2 * MB);    // reuse (ca1 dead after cross ln3)

  const int MROWS = BATCH * SEQ;  // 4096

  // ---- prep ----
  prep_misc<<<8528, 256, 0, stream>>>(x, xh, xl, mem, memb, idx,
                                      sbq, sbk, biasqk, cbk, cbv, cbkv);
  {
    PrepW p;
    p.s2[0] = sWq; p.dh2[0] = WqkhT;               p.dl2[0] = WqklT;
    p.s2[1] = sWk; p.dh2[1] = WqkhT + 1024 * 1024; p.dl2[1] = WqklT + 1024 * 1024;
    p.s6[0] = sWv; p.d6[0] = sWvT;
    p.s6[1] = sWo; p.d6[1] = sWoT;
    p.s6[2] = cWq; p.d6[2] = cWqT;
    p.s6[3] = cWk; p.d6[3] = cWkvT;
    p.s6[4] = cWv; p.d6[4] = cWkvT + 1024 * 1024;
    p.s6[5] = cWo; p.d6[5] = cWoT;
    p.W1 = W1; p.W1T = W1T; p.W2 = W2; p.W2T = W2T;
    prep_weights<<<4096, 256, 0, stream>>>(p);
  }

  // ---- self attention (ProbSparse) ----
  gemm4(xh, xl, WqkhT, WqklT, biasqk, qk, MROWS, 2048, DMODEL, stream);
  gemm(xh, sWvT, sbv, nullptr, vbf, MROWS, DMODEL, DMODEL, 0, stream);
  probM_kernel<<<BATCH * SEQ / 4, 256, 0, stream>>>(qk, idx, Mv);
  topk_kernel<<<BATCH * NHEADS, 256, 0, stream>>>(Mv, Mtop);
  kvpack_self<<<dim3(BATCH * NHEADS, SEQ / 64), 256, 0, stream>>>(qk, vbf, kpks, vpks);
  probAttn_kernel<<<dim3(BATCH * NHEADS, 8), 256, 0, stream>>>(qk, kpks, vpks, Mtop, Opart, mlbuf);
  scanA_kernel<<<dim3(BATCH * NHEADS, 16), 64, 0, stream>>>(vbf, csum);
  scanB_kernel<<<dim3(BATCH * NHEADS, 16), 64, 0, stream>>>(vbf, csum, ctxb);
  probCombine_kernel<<<BATCH * NHEADS * NTOP, 64, 0, stream>>>(Opart, mlbuf, Mtop, ctxb);
  gemm(ctxb, sWoT, sbo, sa, nullptr, MROWS, DMODEL, DMODEL, 0, stream);
  ln_kernel<<<MROWS, 256, 0, stream>>>(x, sa, g1, be1, x1, x1b);

  // ---- cross attention ----
  gemm(x1b, cWqT, cbq, q2, nullptr, MROWS, DMODEL, DMODEL, 0, stream);
  gemm(memb, cWkvT, cbkv, nullptr, kv2b, MROWS, 2048, DMODEL, 0, stream, 1);
  kvpack_kernel<<<dim3(BATCH * NHEADS, SEQ / 64), 256, 0, stream>>>(kv2b, kpk, vpk);
  cross_attn_kernel<<<dim3(BATCH * NHEADS, SEQ / 128), 512, 0, stream>>>(q2, kpk, vpk, cab);
  gemmks(cab, cWoT, cbo, ca0, ca1, MROWS, DMODEL, DMODEL, stream);
  ln3_kernel<<<MROWS, 256, 0, stream>>>(x1, ca0, ca1, g2, be2, x2, x2b);

  // ---- FFN ----
  gemm(x2b, W1T, b1, nullptr, hbb, MROWS, DFF, DMODEL, 1, stream, 1);
  gemmks(hbb, W2T, b2, yb0, yb1, MROWS, DMODEL, DFF, stream);
  ln3_kernel<<<MROWS, 256, 0, stream>>>(x2, yb0, yb1, g3, be3, outp, nullptr);
}